// Round 5
// baseline (713.776 us; speedup 1.0000x reference)
//
#include <hip/hip_runtime.h>

#define B_    2
#define SEQ_  2048
#define H_    32
#define HKV_  8
#define D_    128
#define BLK_  64
#define NB_   32
#define LOCAL_ 16
#define VERT_  8

#define PSTR 72    // P LDS row stride (v1 fallback only)
#define NTASK 512

typedef __attribute__((ext_vector_type(8))) short bf16x8;
typedef __attribute__((ext_vector_type(4))) float f32x4;
typedef __attribute__((ext_vector_type(16))) float f32x16;

__device__ __forceinline__ unsigned short f2bf(float f) {
    union { float f; unsigned u; } x; x.f = f;
    unsigned u = x.u;
    return (unsigned short)((u + 0x7FFFu + ((u >> 16) & 1u)) >> 16);
}

__device__ __forceinline__ unsigned pk2(float a, float b) {
#if defined(__has_builtin) && __has_builtin(__builtin_amdgcn_cvt_pk_bf16_f32)
    typedef __attribute__((ext_vector_type(2))) __bf16 bf2;
    bf2 r = __builtin_amdgcn_cvt_pk_bf16_f32(a, b);
    unsigned u; __builtin_memcpy(&u, &r, 4); return u;
#else
    return (unsigned)f2bf(a) | ((unsigned)f2bf(b) << 16);
#endif
}

// v_permlane32_swap_b32 a, b : new a[32:63] = old b[0:31]; new b[0:31] = old a[32:63].
__device__ __forceinline__ void pswap(unsigned &a, unsigned &b) {
#if defined(__has_builtin) && __has_builtin(__builtin_amdgcn_permlane32_swap)
    auto r = __builtin_amdgcn_permlane32_swap((int)a, (int)b, false, false);
    a = (unsigned)r[0]; b = (unsigned)r[1];
#else
    asm("v_permlane32_swap_b32 %0, %1" : "+v"(a), "+v"(b));
#endif
}

__device__ __forceinline__ f32x16 zero16() {
    f32x16 z;
#pragma unroll
    for (int i = 0; i < 16; ++i) z[i] = 0.f;
    return z;
}

__device__ __forceinline__ bool vfor(int q, int j) {
    return (j <= q) && (((q - j) < LOCAL_) || (((j + 1) & (VERT_ - 1)) == 0));
}
__device__ __forceinline__ int next_valid(int qb, int j) {
    for (++j; j <= qb; ++j) if (vfor(qb, j)) return j;
    return qb + 1;
}
// union of valid sets of qb_hi and qb_hi-1
__device__ __forceinline__ int next_valid2(int hi, int j) {
    for (++j; j <= hi; ++j) if (vfor(hi, j) || vfor(hi - 1, j)) return j;
    return hi + 1;
}

// async global->LDS DMA, 16B/lane. ldsptr MUST be wave-uniform (HW places lane i at base+i*16).
__device__ __forceinline__ void dma16(const unsigned short* g, unsigned short* l) {
    __builtin_amdgcn_global_load_lds(
        (const __attribute__((address_space(1))) unsigned int*)g,
        (__attribute__((address_space(3))) unsigned int*)l, 16, 0, 0);
}

// ============ prepass: K -> bf16 swizzled rows; V -> bf16 transposed+swizzled tiles ============
// K_ws layout: [(b*8+hkv)*2048 + row][128], row's 16 16B-chunks stored at chunk^(row&15).
// V_ws layout: [(b*8+hkv)*32 + jb][d=0..127][64 pos], d-row's 8 16B-chunks stored at chunk^(d&7).
__global__ __launch_bounds__(256)
void prepass_kernel(const float* __restrict__ kg, const float* __restrict__ vg,
                    unsigned short* __restrict__ Kws, unsigned short* __restrict__ Vws) {
    __shared__ unsigned short Vt[D_ * 72];   // [d][pos], padded
    const int bid = blockIdx.x;
    const int b   = bid >> 8;
    const int hkv = (bid >> 5) & 7;
    const int jb  = bid & 31;
    const int tid = threadIdx.x;
    const int rs  = HKV_ * D_;   // fp32 row stride

    const float* kbase = kg + ((size_t)(b * SEQ_ + jb * BLK_) * HKV_ + hkv) * D_;
    const float* vbase = vg + ((size_t)(b * SEQ_ + jb * BLK_) * HKV_ + hkv) * D_;
    unsigned short* Kdst = Kws + ((size_t)(b * 8 + hkv) * SEQ_ + jb * BLK_) * D_;
    unsigned short* Vdst = Vws + ((size_t)(b * 8 + hkv) * NB_ + jb) * (D_ * BLK_);

#pragma unroll
    for (int t = 0; t < 4; ++t) {           // K: 1024 chunks of 8 elems
        const int q = t * 256 + tid;
        const int row = q >> 4, c = q & 15;
        const float* p = kbase + (size_t)row * rs + c * 8;
        const float4 a = *(const float4*)p;
        const float4 d4 = *(const float4*)(p + 4);
        uint4 u = { pk2(a.x, a.y), pk2(a.z, a.w), pk2(d4.x, d4.y), pk2(d4.z, d4.w) };
        *(uint4*)&Kdst[row * 128 + ((c ^ (row & 15)) << 3)] = u;
    }
#pragma unroll
    for (int t = 0; t < 8; ++t) {           // V: load + transpose into LDS
        const int q = t * 256 + tid;
        const int pos = q >> 5, c4 = q & 31;
        const float4 v4 = *(const float4*)(vbase + (size_t)pos * rs + c4 * 4);
        const unsigned u0 = pk2(v4.x, v4.y), u1 = pk2(v4.z, v4.w);
        Vt[(c4 * 4 + 0) * 72 + pos] = (unsigned short)u0;
        Vt[(c4 * 4 + 1) * 72 + pos] = (unsigned short)(u0 >> 16);
        Vt[(c4 * 4 + 2) * 72 + pos] = (unsigned short)u1;
        Vt[(c4 * 4 + 3) * 72 + pos] = (unsigned short)(u1 >> 16);
    }
    __syncthreads();
#pragma unroll
    for (int t = 0; t < 4; ++t) {           // V out: 1024 chunks of 8 pos
        const int q = t * 256 + tid;
        const int d = q >> 3, c = q & 7;
        const uint2 q0 = *(const uint2*)&Vt[d * 72 + c * 8];
        const uint2 q1 = *(const uint2*)&Vt[d * 72 + c * 8 + 4];
        uint4 u = { q0.x, q0.y, q1.x, q1.y };
        *(uint4*)&Vdst[d * 64 + ((c ^ (d & 7)) << 3)] = u;
    }
}

// ============ v7s: v3 compute, static XCD-affine map, one task per block (half A/B probe) ====
// bid&7 = hkv -> under round-robin dispatch all 32 blocks of one hkv land on one XCD and
// stream the same 2MB K/V slab -> L2-resident DMA source.
__global__ __launch_bounds__(512, 2)
void sparse_attn_v7s(const float* __restrict__ qg, float* __restrict__ outg,
                     const unsigned short* __restrict__ Kws,
                     const unsigned short* __restrict__ Vws,
                     int bsel) {
    __shared__ __align__(16) unsigned short Kb[2][BLK_ * D_];   // 2 x 16 KB
    __shared__ __align__(16) unsigned short Vb[2][D_ * BLK_];   // 2 x 16 KB

    const int tid  = threadIdx.x;
    const int wave = tid >> 6;
    const int lane = tid & 63;
    const int q5   = lane & 31;
    const int h    = lane >> 5;
    const int hsub = wave >> 1;
    const int rt2  = wave & 1;

    int cskA[8];
#pragma unroll
    for (int dk = 0; dk < 8; ++dk) cskA[dk] = ((((dk * 2) | h) ^ (lane & 15)) << 3);
    int csvB[4];
#pragma unroll
    for (int kc = 0; kc < 4; ++kc) csvB[kc] = ((((kc * 2) | h) ^ (lane & 7)) << 3);

    const float c2 = 0.12751649736230723f;
    const short oneb = (short)0x3F80;
    const bf16x8 ones = {oneb, oneb, oneb, oneb, oneb, oneb, oneb, oneb};

    const int bid = blockIdx.x;
    const int hkv = bid & 7;          // XCD-affine
    const int qb  = bid >> 3;         // 0..31
    const int b   = bsel;
    const int head = hkv * 4 + hsub;

    const unsigned short* Kbh = Kws + (size_t)(b * 8 + hkv) * SEQ_ * D_;
    const unsigned short* Vbh = Vws + (size_t)(b * 8 + hkv) * NB_ * (D_ * BLK_);

    int j = next_valid(qb, -1);
    {
        const size_t off = (size_t)j * (BLK_ * D_);
#pragma unroll
        for (int i = 0; i < 2; ++i) {
            dma16(Kbh + off + i * 4096 + tid * 8, &Kb[0][i * 4096 + wave * 512]);
            dma16(Vbh + off + i * 4096 + tid * 8, &Vb[0][i * 4096 + wave * 512]);
        }
    }

    bf16x8 qf[8];
    {
        const int row = qb * BLK_ + rt2 * 32 + q5;
        const float* qp = qg + ((size_t)(b * SEQ_ + row) * H_ + head) * D_ + h * 8;
#pragma unroll
        for (int dk = 0; dk < 8; ++dk) {
            const float4 a = *(const float4*)(qp + dk * 16);
            const float4 c = *(const float4*)(qp + dk * 16 + 4);
            uint4 u = { pk2(a.x, a.y), pk2(a.z, a.w), pk2(c.x, c.y), pk2(c.z, c.w) };
            __builtin_memcpy(&qf[dk], &u, 16);
        }
    }

    f32x16 lacc = zero16();
    f32x16 o_acc[4];
#pragma unroll
    for (int dt = 0; dt < 4; ++dt) o_acc[dt] = zero16();

    __syncthreads();
    int it = 0;
    while (j <= qb) {
        const int jn = next_valid(qb, j);
        const int cur = it & 1;
        if (jn <= qb) {
            const size_t off = (size_t)jn * (BLK_ * D_);
#pragma unroll
            for (int i = 0; i < 2; ++i) {
                dma16(Kbh + off + i * 4096 + tid * 8, &Kb[cur ^ 1][i * 4096 + wave * 512]);
                dma16(Vbh + off + i * 4096 + tid * 8, &Vb[cur ^ 1][i * 4096 + wave * 512]);
            }
        }

        const bool diag  = (j == qb);
        const bool diagw = diag && (rt2 == 0);

        const unsigned short* kb = Kb[cur];
        f32x16 s0 = zero16(), s1 = zero16();
        {
            const unsigned short* k0r = kb + q5 * 128;
            const unsigned short* k1r = kb + (32 + q5) * 128;
#pragma unroll
            for (int dk = 0; dk < 8; ++dk) {
                const bf16x8 kf0 = *(const bf16x8*)(k0r + cskA[dk]);
                s0 = __builtin_amdgcn_mfma_f32_32x32x16_bf16(kf0, qf[dk], s0, 0, 0, 0);
            }
            if (!diagw) {
#pragma unroll
                for (int dk = 0; dk < 8; ++dk) {
                    const bf16x8 kf1 = *(const bf16x8*)(k1r + cskA[dk]);
                    s1 = __builtin_amdgcn_mfma_f32_32x32x16_bf16(kf1, qf[dk], s1, 0, 0, 0);
                }
            }
        }

        if (diag) {
            if (rt2 == 0) {
#pragma unroll
                for (int r = 0; r < 16; ++r) {
                    const int crow = (r & 3) + 8 * (r >> 2) + 4 * h;
                    if (crow > q5) s0[r] = -INFINITY;
                }
            } else {
#pragma unroll
                for (int r = 0; r < 16; ++r) {
                    const int crow = (r & 3) + 8 * (r >> 2) + 4 * h;
                    if (crow > q5) s1[r] = -INFINITY;
                }
            }
        }

#pragma unroll
        for (int r = 0; r < 16; ++r) s0[r] = exp2f(s0[r] * c2);
        if (!diagw) {
#pragma unroll
            for (int r = 0; r < 16; ++r) s1[r] = exp2f(s1[r] * c2);
        }

        bf16x8 pa[4];
#pragma unroll
        for (int kc = 0; kc < 4; ++kc) {
            if (kc >= 2 && diagw) continue;
            const f32x16 &pp = (kc >= 2) ? s1 : s0;
            const int b0 = (kc & 1) * 8;
            unsigned A0 = pk2(pp[b0 + 0], pp[b0 + 1]);
            unsigned B0 = pk2(pp[b0 + 4], pp[b0 + 5]);
            unsigned A1 = pk2(pp[b0 + 2], pp[b0 + 3]);
            unsigned B1 = pk2(pp[b0 + 6], pp[b0 + 7]);
            pswap(A0, B0);
            pswap(A1, B1);
            uint4 u = { A0, A1, B0, B1 };
            __builtin_memcpy(&pa[kc], &u, 16);
            lacc = __builtin_amdgcn_mfma_f32_32x32x16_bf16(pa[kc], ones, lacc, 0, 0, 0);
        }

        const unsigned short* vb = Vb[cur];
#pragma unroll
        for (int dt = 0; dt < 4; ++dt) {
            const unsigned short* vrow = vb + (dt * 32 + q5) * 64;
#pragma unroll
            for (int kc = 0; kc < 4; ++kc) {
                if (kc >= 2 && diagw) continue;
                const bf16x8 vf = *(const bf16x8*)(vrow + csvB[kc]);
                o_acc[dt] = __builtin_amdgcn_mfma_f32_32x32x16_bf16(pa[kc], vf, o_acc[dt], 0, 0, 0);
            }
        }

        __syncthreads();
        j = jn; ++it;
    }

    const int rowbase = qb * BLK_ + rt2 * 32;
#pragma unroll
    for (int r = 0; r < 16; ++r) {
        const int row = rowbase + (r & 3) + 8 * (r >> 2) + 4 * h;
        const float inv = 1.0f / lacc[r];
        float* op = outg + ((size_t)(b * SEQ_ + row) * H_ + head) * D_ + q5;
        op[0]  = o_acc[0][r] * inv;
        op[32] = o_acc[1][r] * inv;
        op[64] = o_acc[2][r] * inv;
        op[96] = o_acc[3][r] * inv;
    }
}

// ============ v7p: qb-PAIR kernel — 1024 thr, 16 waves, one block serves 128 q-rows x 4 heads
// from ONE staged K/V stream (j-union of qb-pair, ~46% DMA bytes saved vs two v3 tasks).
// wave = hsub*4 + rt4; rt4 = 32-row tile of the 128-row pair region; qb_w = 2*qbp + (rt4>>1).
// Waves whose qb_w doesn't attend tile j skip compute (wave-uniform) but still STAGE+barrier.
// Per-wave code identical to v3 (104 VGPR < 128 cap for 16-wave residency).
__global__ __launch_bounds__(1024)
void sparse_attn_v7p(const float* __restrict__ qg, float* __restrict__ outg,
                     const unsigned short* __restrict__ Kws,
                     const unsigned short* __restrict__ Vws,
                     int bsel) {
    __shared__ __align__(16) unsigned short Kb[2][BLK_ * D_];   // 2 x 16 KB
    __shared__ __align__(16) unsigned short Vb[2][D_ * BLK_];   // 2 x 16 KB

    const int tid  = threadIdx.x;
    const int wave = tid >> 6;
    const int lane = tid & 63;
    const int q5   = lane & 31;
    const int h    = lane >> 5;
    const int hsub = wave >> 2;       // 0..3 head within GQA group
    const int rt4  = wave & 3;        // 0..3 row-tile of 32 within the 128-row pair

    int cskA[8];
#pragma unroll
    for (int dk = 0; dk < 8; ++dk) cskA[dk] = ((((dk * 2) | h) ^ (lane & 15)) << 3);
    int csvB[4];
#pragma unroll
    for (int kc = 0; kc < 4; ++kc) csvB[kc] = ((((kc * 2) | h) ^ (lane & 7)) << 3);

    const float c2 = 0.12751649736230723f;
    const short oneb = (short)0x3F80;
    const bf16x8 ones = {oneb, oneb, oneb, oneb, oneb, oneb, oneb, oneb};

    const int bid = blockIdx.x;       // 0..127
    const int hkv = bid & 7;          // XCD-affine
    const int qbp = bid >> 3;         // 0..15
    const int hi  = qbp * 2 + 1;
    const int qb_w = qbp * 2 + (rt4 >> 1);
    const int rt2 = rt4 & 1;
    const int b   = bsel;
    const int head = hkv * 4 + hsub;

    const unsigned short* Kbh = Kws + (size_t)(b * 8 + hkv) * SEQ_ * D_;
    const unsigned short* Vbh = Vws + (size_t)(b * 8 + hkv) * NB_ * (D_ * BLK_);

    int j = next_valid2(hi, -1);
    {   // 1024 thr: one dma16 per wave covers the 16KB tile
        const size_t off = (size_t)j * (BLK_ * D_);
        dma16(Kbh + off + tid * 8, &Kb[0][wave * 512]);
        dma16(Vbh + off + tid * 8, &Vb[0][wave * 512]);
    }

    bf16x8 qf[8];
    {
        const int row = qbp * 128 + rt4 * 32 + q5;
        const float* qp = qg + ((size_t)(b * SEQ_ + row) * H_ + head) * D_ + h * 8;
#pragma unroll
        for (int dk = 0; dk < 8; ++dk) {
            const float4 a = *(const float4*)(qp + dk * 16);
            const float4 c = *(const float4*)(qp + dk * 16 + 4);
            uint4 u = { pk2(a.x, a.y), pk2(a.z, a.w), pk2(c.x, c.y), pk2(c.z, c.w) };
            __builtin_memcpy(&qf[dk], &u, 16);
        }
    }

    f32x16 lacc = zero16();
    f32x16 o_acc[4];
#pragma unroll
    for (int dt = 0; dt < 4; ++dt) o_acc[dt] = zero16();

    __syncthreads();
    int it = 0;
    while (j <= hi) {
        const int jn = next_valid2(hi, j);
        const int cur = it & 1;
        if (jn <= hi) {
            const size_t off = (size_t)jn * (BLK_ * D_);
            dma16(Kbh + off + tid * 8, &Kb[cur ^ 1][wave * 512]);
            dma16(Vbh + off + tid * 8, &Vb[cur ^ 1][wave * 512]);
        }

        if (vfor(qb_w, j)) {   // wave-uniform: this wave's qb attends tile j
            const bool diag  = (j == qb_w);
            const bool diagw = diag && (rt2 == 0);

            const unsigned short* kb = Kb[cur];
            f32x16 s0 = zero16(), s1 = zero16();
            {
                const unsigned short* k0r = kb + q5 * 128;
                const unsigned short* k1r = kb + (32 + q5) * 128;
#pragma unroll
                for (int dk = 0; dk < 8; ++dk) {
                    const bf16x8 kf0 = *(const bf16x8*)(k0r + cskA[dk]);
                    s0 = __builtin_amdgcn_mfma_f32_32x32x16_bf16(kf0, qf[dk], s0, 0, 0, 0);
                }
                if (!diagw) {
#pragma unroll
                    for (int dk = 0; dk < 8; ++dk) {
                        const bf16x8 kf1 = *(const bf16x8*)(k1r + cskA[dk]);
                        s1 = __builtin_amdgcn_mfma_f32_32x32x16_bf16(kf1, qf[dk], s1, 0, 0, 0);
                    }
                }
            }

            if (diag) {
                if (rt2 == 0) {
#pragma unroll
                    for (int r = 0; r < 16; ++r) {
                        const int crow = (r & 3) + 8 * (r >> 2) + 4 * h;
                        if (crow > q5) s0[r] = -INFINITY;
                    }
                } else {
#pragma unroll
                    for (int r = 0; r < 16; ++r) {
                        const int crow = (r & 3) + 8 * (r >> 2) + 4 * h;
                        if (crow > q5) s1[r] = -INFINITY;
                    }
                }
            }

#pragma unroll
            for (int r = 0; r < 16; ++r) s0[r] = exp2f(s0[r] * c2);
            if (!diagw) {
#pragma unroll
                for (int r = 0; r < 16; ++r) s1[r] = exp2f(s1[r] * c2);
            }

            bf16x8 pa[4];
#pragma unroll
            for (int kc = 0; kc < 4; ++kc) {
                if (kc >= 2 && diagw) continue;
                const f32x16 &pp = (kc >= 2) ? s1 : s0;
                const int b0 = (kc & 1) * 8;
                unsigned A0 = pk2(pp[b0 + 0], pp[b0 + 1]);
                unsigned B0 = pk2(pp[b0 + 4], pp[b0 + 5]);
                unsigned A1 = pk2(pp[b0 + 2], pp[b0 + 3]);
                unsigned B1 = pk2(pp[b0 + 6], pp[b0 + 7]);
                pswap(A0, B0);
                pswap(A1, B1);
                uint4 u = { A0, A1, B0, B1 };
                __builtin_memcpy(&pa[kc], &u, 16);
                lacc = __builtin_amdgcn_mfma_f32_32x32x16_bf16(pa[kc], ones, lacc, 0, 0, 0);
            }

            const unsigned short* vb = Vb[cur];
#pragma unroll
            for (int dt = 0; dt < 4; ++dt) {
                const unsigned short* vrow = vb + (dt * 32 + q5) * 64;
#pragma unroll
                for (int kc = 0; kc < 4; ++kc) {
                    if (kc >= 2 && diagw) continue;
                    const bf16x8 vf = *(const bf16x8*)(vrow + csvB[kc]);
                    o_acc[dt] = __builtin_amdgcn_mfma_f32_32x32x16_bf16(pa[kc], vf, o_acc[dt], 0, 0, 0);
                }
            }
        }

        __syncthreads();
        j = jn; ++it;
    }

    const int rowbase = qbp * 128 + rt4 * 32;
#pragma unroll
    for (int r = 0; r < 16; ++r) {
        const int row = rowbase + (r & 3) + 8 * (r >> 2) + 4 * h;
        const float inv = 1.0f / lacc[r];
        float* op = outg + ((size_t)(b * SEQ_ + row) * H_ + head) * D_ + q5;
        op[0]  = o_acc[0][r] * inv;
        op[32] = o_acc[1][r] * inv;
        op[64] = o_acc[2][r] * inv;
        op[96] = o_acc[3][r] * inv;
    }
}

// ============ fallback (no workspace): round-4 kernel, unchanged ============
#define KSTR 136
#define VSTR 72
__global__ __launch_bounds__(1024)
void sparse_attn_v1(const float* __restrict__ qg, const float* __restrict__ kg,
                    const float* __restrict__ vg, float* __restrict__ outg,
                    unsigned* __restrict__ ctr) {
    __shared__ __align__(16) unsigned short Klds[BLK_ * KSTR];
    __shared__ __align__(16) unsigned short Vlds[D_ * VSTR];
    __shared__ __align__(16) unsigned short Plds[16 * 16 * PSTR];
    __shared__ unsigned taskLds;

    const int tid  = threadIdx.x;
    const int wave = tid >> 6;
    const int lane = tid & 63;
    const int l15  = lane & 15;
    const int quad = lane >> 4;
    const int hsub = wave >> 2;
    const int rt   = wave & 3;

    const int srow0 = tid >> 5, srow1 = srow0 + 32;
    const int sc4   = tid & 31;
    const int kld0  = srow0 * KSTR + sc4 * 4, kld1 = srow1 * KSTR + sc4 * 4;
    const int vd    = sc4 * 4;
    const int vskew = (sc4 & 7) << 3;
    const int vp0   = (srow0 + vskew) & 63, vp1 = (srow1 + vskew) & 63;
    const size_t stoff0 = (size_t)srow0 * (HKV_ * D_) + sc4 * 4;
    const size_t stoff1 = (size_t)srow1 * (HKV_ * D_) + sc4 * 4;

    const float c2 = 0.12751649736230723f;
    const short oneb = (short)0x3F80;
    const bf16x8 ones = {oneb, oneb, oneb, oneb, oneb, oneb, oneb, oneb};
    unsigned short* pl = &Plds[wave * 16 * PSTR];

    for (;;) {
        __syncthreads();
        if (tid == 0) taskLds = atomicAdd(ctr, 1u);
        __syncthreads();
        const unsigned t = taskLds;
        if (t >= NTASK) break;
        const int qb  = 31 - (int)(t >> 4);
        const int bh  = (int)(t & 15);
        const int b   = bh >> 3;
        const int hkv = bh & 7;
        const int head = hkv * 4 + hsub;
        const float* kbase = kg + ((size_t)(b * SEQ_) * HKV_ + hkv) * D_;
        const float* vbase = vg + ((size_t)(b * SEQ_) * HKV_ + hkv) * D_;
        bf16x8 qf[4];
        {
            const int row = qb * BLK_ + rt * 16 + l15;
            const float* qp = qg + ((size_t)(b * SEQ_ + row) * H_ + head) * D_;
#pragma unroll
            for (int s = 0; s < 4; ++s) {
                const float4 a = *(const float4*)(qp + s * 32 + quad * 8);
                const float4 c = *(const float4*)(qp + s * 32 + quad * 8 + 4);
                uint4 u = { pk2(a.x, a.y), pk2(a.z, a.w), pk2(c.x, c.y), pk2(c.z, c.w) };
                __builtin_memcpy(&qf[s], &u, 16);
            }
        }
        f32x4 lacc = f32x4{0.f, 0.f, 0.f, 0.f};
        f32x4 o_acc[8];
#pragma unroll
        for (int t8 = 0; t8 < 8; ++t8) o_acc[t8] = f32x4{0.f, 0.f, 0.f, 0.f};
        int j = next_valid(qb, -1);
        float4 kpr0, kpr1, vpr0, vpr1;
        {
            const float* kp = kbase + (size_t)j * BLK_ * HKV_ * D_;
            const float* vp = vbase + (size_t)j * BLK_ * HKV_ * D_;
            kpr0 = *(const float4*)(kp + stoff0); kpr1 = *(const float4*)(kp + stoff1);
            vpr0 = *(const float4*)(vp + stoff0); vpr1 = *(const float4*)(vp + stoff1);
        }
        while (j <= qb) {
            const int jn = next_valid(qb, j);
            __syncthreads();
            {
                uint2 u0 = { pk2(kpr0.x, kpr0.y), pk2(kpr0.z, kpr0.w) };
                uint2 u1 = { pk2(kpr1.x, kpr1.y), pk2(kpr1.z, kpr1.w) };
                *(uint2*)&Klds[kld0] = u0;
                *(uint2*)&Klds[kld1] = u1;
                unsigned a0 = pk2(vpr0.x, vpr0.y), a1 = pk2(vpr0.z, vpr0.w);
                Vlds[(vd + 0) * VSTR + vp0] = (unsigned short)a0;
                Vlds[(vd + 1) * VSTR + vp0] = (unsigned short)(a0 >> 16);
                Vlds[(vd + 2) * VSTR + vp0] = (unsigned short)a1;
                Vlds[(vd + 3) * VSTR + vp0] = (unsigned short)(a1 >> 16);
                unsigned b0 = pk2(vpr1.x, vpr1.y), b1 = pk2(vpr1.z, vpr1.w);
                Vlds[(vd + 0) * VSTR + vp1] = (unsigned short)b0;
                Vlds[(vd + 1) * VSTR + vp1] = (unsigned short)(b0 >> 16);
                Vlds[(vd + 2) * VSTR + vp1] = (unsigned short)b1;
                Vlds[(vd + 3) * VSTR + vp1] = (unsigned short)(b1 >> 16);
            }
            __syncthreads();
            if (jn <= qb) {
                const float* kp = kbase + (size_t)jn * BLK_ * HKV_ * D_;
                const float* vp = vbase + (size_t)jn * BLK_ * HKV_ * D_;
                kpr0 = *(const float4*)(kp + stoff0); kpr1 = *(const float4*)(kp + stoff1);
                vpr0 = *(const float4*)(vp + stoff0); vpr1 = *(const float4*)(vp + stoff1);
            }
            f32x4 sacc[4];
#pragma unroll
            for (int t4 = 0; t4 < 4; ++t4) {
                f32x4 acc = f32x4{0.f, 0.f, 0.f, 0.f};
#pragma unroll
                for (int s = 0; s < 4; ++s) {
                    const bf16x8 kf = *(const bf16x8*)&Klds[(t4 * 16 + l15) * KSTR + s * 32 + quad * 8];
                    acc = __builtin_amdgcn_mfma_f32_16x16x32_bf16(qf[s], kf, acc, 0, 0, 0);
                }
                sacc[t4] = acc;
            }
            if (j == qb) {
                const int rowbase = rt * 16 + quad * 4;
#pragma unroll
                for (int t4 = 0; t4 < 4; ++t4) {
                    const int col = t4 * 16 + l15;
#pragma unroll
                    for (int r = 0; r < 4; ++r)
                        if (col > rowbase + r) sacc[t4][r] = -INFINITY;
                }
            }
#pragma unroll
            for (int t4 = 0; t4 < 4; ++t4) {
                const float p0 = exp2f(sacc[t4][0] * c2);
                const float p1 = exp2f(sacc[t4][1] * c2);
                const float p2 = exp2f(sacc[t4][2] * c2);
                const float p3 = exp2f(sacc[t4][3] * c2);
                const unsigned u01 = pk2(p0, p1), u23 = pk2(p2, p3);
                const int cb = t4 * 16 + l15;
                pl[(quad * 4 + 0) * PSTR + cb] = (unsigned short)u01;
                pl[(quad * 4 + 1) * PSTR + cb] = (unsigned short)(u01 >> 16);
                pl[(quad * 4 + 2) * PSTR + cb] = (unsigned short)u23;
                pl[(quad * 4 + 3) * PSTR + cb] = (unsigned short)(u23 >> 16);
            }
#pragma unroll
            for (int s2 = 0; s2 < 2; ++s2) {
                const bf16x8 pf = *(const bf16x8*)&pl[l15 * PSTR + s2 * 32 + quad * 8];
                lacc = __builtin_amdgcn_mfma_f32_16x16x32_bf16(pf, ones, lacc, 0, 0, 0);
                const int k0 = s2 * 32 + quad * 8;
#pragma unroll
                for (int t8 = 0; t8 < 8; ++t8) {
                    const int n  = t8 * 16 + l15;
                    const int p2 = (k0 + (((n >> 2) & 7) << 3)) & 63;
                    const bf16x8 vf = *(const bf16x8*)&Vlds[n * VSTR + p2];
                    o_acc[t8] = __builtin_amdgcn_mfma_f32_16x16x32_bf16(pf, vf, o_acc[t8], 0, 0, 0);
                }
            }
            j = jn;
        }
        const int orow = qb * BLK_ + rt * 16 + quad * 4;
#pragma unroll
        for (int r = 0; r < 4; ++r) {
            const float inv_l = 1.0f / lacc[r];
            float* op = outg + ((size_t)(b * SEQ_ + orow + r) * H_ + head) * D_;
#pragma unroll
            for (int t8 = 0; t8 < 8; ++t8)
                op[t8 * 16 + l15] = o_acc[t8][r] * inv_l;
        }
    }
}

extern "C" void kernel_launch(void* const* d_in, const int* in_sizes, int n_in,
                              void* d_out, int out_size, void* d_ws, size_t ws_size,
                              hipStream_t stream) {
    const float* q = (const float*)d_in[0];
    const float* k = (const float*)d_in[1];
    const float* v = (const float*)d_in[2];
    float* out = (float*)d_out;

    const size_t kws_elems = (size_t)B_ * HKV_ * SEQ_ * D_;   // 4,194,304 bf16
    const size_t need = 256 + 2 * kws_elems * sizeof(unsigned short);
    if (ws_size >= need) {
        unsigned short* Kws = (unsigned short*)((char*)d_ws + 256);
        unsigned short* Vws = Kws + kws_elems;
        prepass_kernel<<<dim3(B_ * HKV_ * NB_), dim3(256), 0, stream>>>(k, v, Kws, Vws);
        // A/B probe: b=1 via qb-pair kernel (128 blocks), b=0 via single+XCD-affine (256 blocks).
        sparse_attn_v7p<<<dim3(128), dim3(1024), 0, stream>>>(q, out, Kws, Vws, 1);
        sparse_attn_v7s<<<dim3(256), dim3(512), 0, stream>>>(q, out, Kws, Vws, 0);
    } else {
        hipMemsetAsync(d_ws, 0, sizeof(unsigned), stream);
        sparse_attn_v1<<<dim3(256), dim3(1024), 0, stream>>>(q, k, v, out, (unsigned*)d_ws);
    }
}

// Round 6
// 300.430 us; speedup vs baseline: 2.3758x; 2.3758x over previous
//
#include <hip/hip_runtime.h>

#define B_    2
#define SEQ_  2048
#define H_    32
#define HKV_  8
#define D_    128
#define BLK_  64
#define NB_   32
#define LOCAL_ 16
#define VERT_  8

#define PSTR 72    // P LDS row stride (v1 fallback only)
#define NTASK 512
#define NBLOCK 512   // 2 blocks/CU target (regs <=128/wave via launch_bounds(512,4))

typedef __attribute__((ext_vector_type(8))) short bf16x8;
typedef __attribute__((ext_vector_type(4))) float f32x4;
typedef __attribute__((ext_vector_type(16))) float f32x16;

__device__ __forceinline__ unsigned short f2bf(float f) {
    union { float f; unsigned u; } x; x.f = f;
    unsigned u = x.u;
    return (unsigned short)((u + 0x7FFFu + ((u >> 16) & 1u)) >> 16);
}

__device__ __forceinline__ unsigned pk2(float a, float b) {
#if defined(__has_builtin) && __has_builtin(__builtin_amdgcn_cvt_pk_bf16_f32)
    typedef __attribute__((ext_vector_type(2))) __bf16 bf2;
    bf2 r = __builtin_amdgcn_cvt_pk_bf16_f32(a, b);
    unsigned u; __builtin_memcpy(&u, &r, 4); return u;
#else
    return (unsigned)f2bf(a) | ((unsigned)f2bf(b) << 16);
#endif
}

// v_permlane32_swap_b32 a, b : new a[32:63] = old b[0:31]; new b[0:31] = old a[32:63].
__device__ __forceinline__ void pswap(unsigned &a, unsigned &b) {
#if defined(__has_builtin) && __has_builtin(__builtin_amdgcn_permlane32_swap)
    auto r = __builtin_amdgcn_permlane32_swap((int)a, (int)b, false, false);
    a = (unsigned)r[0]; b = (unsigned)r[1];
#else
    asm("v_permlane32_swap_b32 %0, %1" : "+v"(a), "+v"(b));
#endif
}

// bf16 halves of a pk2 word back to f32 (exact)
__device__ __forceinline__ float bflo(unsigned u) {
    unsigned v = u << 16; float f; __builtin_memcpy(&f, &v, 4); return f;
}
__device__ __forceinline__ float bfhi(unsigned u) {
    unsigned v = u & 0xFFFF0000u; float f; __builtin_memcpy(&f, &v, 4); return f;
}

__device__ __forceinline__ f32x16 zero16() {
    f32x16 z;
#pragma unroll
    for (int i = 0; i < 16; ++i) z[i] = 0.f;
    return z;
}

__device__ __forceinline__ int next_valid(int qb, int j) {
    for (++j; j <= qb; ++j)
        if (((qb - j) < LOCAL_) || (((j + 1) & (VERT_ - 1)) == 0)) return j;
    return qb + 1;
}

// async global->LDS DMA, 16B/lane. ldsptr MUST be wave-uniform (HW places lane i at base+i*16).
__device__ __forceinline__ void dma16(const unsigned short* g, unsigned short* l) {
    __builtin_amdgcn_global_load_lds(
        (const __attribute__((address_space(1))) unsigned int*)g,
        (__attribute__((address_space(3))) unsigned int*)l, 16, 0, 0);
}

// ============ prepass: K -> bf16 swizzled rows; V -> bf16 transposed+swizzled tiles ============
// K_ws layout: [(b*8+hkv)*2048 + row][128], row's 16 16B-chunks stored at chunk^(row&15).
// V_ws layout: [(b*8+hkv)*32 + jb][d=0..127][64 pos], d-row's 8 16B-chunks stored at chunk^(d&7).
__global__ __launch_bounds__(256)
void prepass_kernel(const float* __restrict__ kg, const float* __restrict__ vg,
                    unsigned short* __restrict__ Kws, unsigned short* __restrict__ Vws) {
    __shared__ unsigned short Vt[D_ * 72];   // [d][pos], padded
    const int bid = blockIdx.x;
    const int b   = bid >> 8;
    const int hkv = (bid >> 5) & 7;
    const int jb  = bid & 31;
    const int tid = threadIdx.x;
    const int rs  = HKV_ * D_;   // fp32 row stride

    const float* kbase = kg + ((size_t)(b * SEQ_ + jb * BLK_) * HKV_ + hkv) * D_;
    const float* vbase = vg + ((size_t)(b * SEQ_ + jb * BLK_) * HKV_ + hkv) * D_;
    unsigned short* Kdst = Kws + ((size_t)(b * 8 + hkv) * SEQ_ + jb * BLK_) * D_;
    unsigned short* Vdst = Vws + ((size_t)(b * 8 + hkv) * NB_ + jb) * (D_ * BLK_);

#pragma unroll
    for (int t = 0; t < 4; ++t) {           // K: 1024 chunks of 8 elems
        const int q = t * 256 + tid;
        const int row = q >> 4, c = q & 15;
        const float* p = kbase + (size_t)row * rs + c * 8;
        const float4 a = *(const float4*)p;
        const float4 d4 = *(const float4*)(p + 4);
        uint4 u = { pk2(a.x, a.y), pk2(a.z, a.w), pk2(d4.x, d4.y), pk2(d4.z, d4.w) };
        *(uint4*)&Kdst[row * 128 + ((c ^ (row & 15)) << 3)] = u;
    }
#pragma unroll
    for (int t = 0; t < 8; ++t) {           // V: load + transpose into LDS
        const int q = t * 256 + tid;
        const int pos = q >> 5, c4 = q & 31;
        const float4 v4 = *(const float4*)(vbase + (size_t)pos * rs + c4 * 4);
        const unsigned u0 = pk2(v4.x, v4.y), u1 = pk2(v4.z, v4.w);
        Vt[(c4 * 4 + 0) * 72 + pos] = (unsigned short)u0;
        Vt[(c4 * 4 + 1) * 72 + pos] = (unsigned short)(u0 >> 16);
        Vt[(c4 * 4 + 2) * 72 + pos] = (unsigned short)u1;
        Vt[(c4 * 4 + 3) * 72 + pos] = (unsigned short)(u1 >> 16);
    }
    __syncthreads();
#pragma unroll
    for (int t = 0; t < 4; ++t) {           // V out: 1024 chunks of 8 pos
        const int q = t * 256 + tid;
        const int d = q >> 3, c = q & 7;
        const uint2 q0 = *(const uint2*)&Vt[d * 72 + c * 8];
        const uint2 q1 = *(const uint2*)&Vt[d * 72 + c * 8 + 4];
        uint4 u = { q0.x, q0.y, q1.x, q1.y };
        *(uint4*)&Vdst[d * 64 + ((c ^ (d & 7)) << 3)] = u;
    }
}

// ============ main kernel v8: v3 compute on a register diet -> 2 blocks/CU ============
// Diet vs v3 (~184 regs -> target <=128, launch_bounds(512,4)):
//  - l via VALU: accumulate llane from the PRE-swap pk2 words (bf16-rounded, identical
//    numerics to the old mfma(pa,ones)); epilogue: permlane32_swap + ds_bpermute.
//    Kills lacc(16) + ones(4) regs and 4 MFMA/window.
//  - k-half-sequential S: one f32x16 s (16 regs) instead of s0+s1 (32).
//  - pack-inline pa (4 regs live), kc-outer/dt-inner PV (4 independent o_acc chains).
//  - swizzle chunk offsets recomputed inline (remat under pressure).
// Sync structure = v3's proven __syncthreads double-buffer (one variable this round).
__global__ __launch_bounds__(512, 4)
void sparse_attn_v8(const float* __restrict__ qg, float* __restrict__ outg,
                    const unsigned short* __restrict__ Kws,
                    const unsigned short* __restrict__ Vws,
                    unsigned* __restrict__ ctr) {
    __shared__ __align__(16) unsigned short Kb[2][BLK_ * D_];   // 2 x 16 KB
    __shared__ __align__(16) unsigned short Vb[2][D_ * BLK_];   // 2 x 16 KB
    __shared__ unsigned taskLds;

    const int tid  = threadIdx.x;
    const int wave = tid >> 6;
    const int lane = tid & 63;
    const int q5   = lane & 31;       // q-row within 32-row tile / d-col within 32 / K-row within 32
    const int h    = lane >> 5;       // lane half
    const int l15  = lane & 15;
    const int l7   = lane & 7;
    const int hsub = wave >> 1;
    const int rt2  = wave & 1;

    const float c2 = 0.12751649736230723f;   // (1/sqrt(128)) * log2(e)

    for (;;) {
        __syncthreads();
        if (tid == 0) taskLds = atomicAdd(ctr, 1u);
        __syncthreads();
        const unsigned t = taskLds;
        if (t >= NTASK) break;

        const int qb  = 31 - (int)(t >> 4);   // LPT: big tasks first
        const int bh  = (int)(t & 15);
        const int b   = bh >> 3;
        const int hkv = bh & 7;
        const int head = hkv * 4 + hsub;

        const unsigned short* Kbh = Kws + (size_t)(b * 8 + hkv) * SEQ_ * D_;
        const unsigned short* Vbh = Vws + (size_t)(b * 8 + hkv) * NB_ * (D_ * BLK_);

        int j = next_valid(qb, -1);
        // issue first tile DMA into buf0 (latency hidden behind Q load/convert)
        {
            const size_t off = (size_t)j * (BLK_ * D_);
#pragma unroll
            for (int i = 0; i < 2; ++i) {
                dma16(Kbh + off + i * 4096 + tid * 8, &Kb[0][i * 4096 + wave * 512]);
                dma16(Vbh + off + i * 4096 + tid * 8, &Vb[0][i * 4096 + wave * 512]);
            }
        }

        // ---- Q fragments (B-operand layout): q-col = q5, d = dk*16 + h*8 + e
        bf16x8 qf[8];
        {
            const int row = qb * BLK_ + rt2 * 32 + q5;
            const float* qp = qg + ((size_t)(b * SEQ_ + row) * H_ + head) * D_ + h * 8;
#pragma unroll
            for (int dk = 0; dk < 8; ++dk) {
                const float4 a = *(const float4*)(qp + dk * 16);
                const float4 c = *(const float4*)(qp + dk * 16 + 4);
                uint4 u = { pk2(a.x, a.y), pk2(a.z, a.w), pk2(c.x, c.y), pk2(c.z, c.w) };
                __builtin_memcpy(&qf[dk], &u, 16);
            }
        }

        float llane = 0.f;
        f32x16 o_acc[4];
#pragma unroll
        for (int dt = 0; dt < 4; ++dt) o_acc[dt] = zero16();

        __syncthreads();   // drains first DMA (vmcnt(0)) + syncs all waves
        int it = 0;
        while (j <= qb) {
            const int jn = next_valid(qb, j);
            const int cur = it & 1;
            if (jn <= qb) {   // issue next tile into the other buffer (wave-uniform branch)
                const size_t off = (size_t)jn * (BLK_ * D_);
#pragma unroll
                for (int i = 0; i < 2; ++i) {
                    dma16(Kbh + off + i * 4096 + tid * 8, &Kb[cur ^ 1][i * 4096 + wave * 512]);
                    dma16(Vbh + off + i * 4096 + tid * 8, &Vb[cur ^ 1][i * 4096 + wave * 512]);
                }
            }

            const bool diag  = (j == qb);
            const bool diagw = diag && (rt2 == 0);   // upper 32 k-cols fully masked -> skip kh=1
            const unsigned short* kb = Kb[cur];
            const unsigned short* vb = Vb[cur];

            // ---- one 32-col k-half: S^T -> exp -> pack -> PV (s reused across halves)
            auto HALF = [&](int kh, bool maskit) {
                const unsigned short* krow = kb + (kh * 32 + q5) * 128;
                f32x16 s = zero16();
#pragma unroll
                for (int dk = 0; dk < 8; ++dk) {
                    const int ck = ((((dk * 2) | h) ^ l15) << 3);   // swizzled chunk (inline remat)
                    const bf16x8 kf = *(const bf16x8*)(krow + ck);
                    s = __builtin_amdgcn_mfma_f32_32x32x16_bf16(kf, qf[dk], s, 0, 0, 0);
                }
                if (maskit) {
#pragma unroll
                    for (int r = 0; r < 16; ++r) {
                        const int crow = (r & 3) + 8 * (r >> 2) + 4 * h;
                        if (crow > q5) s[r] = -INFINITY;
                    }
                }
#pragma unroll
                for (int r = 0; r < 16; ++r) s[r] = exp2f(s[r] * c2);

#pragma unroll
                for (int kq = 0; kq < 2; ++kq) {
                    const int b0 = kq * 8;
                    unsigned A0 = pk2(s[b0 + 0], s[b0 + 1]);
                    unsigned B0 = pk2(s[b0 + 4], s[b0 + 5]);
                    unsigned A1 = pk2(s[b0 + 2], s[b0 + 3]);
                    unsigned B1 = pk2(s[b0 + 6], s[b0 + 7]);
                    // l accumulate from PRE-swap rounded words (lane-local P-hat values)
                    llane += ((bflo(A0) + bfhi(A0)) + (bflo(B0) + bfhi(B0)))
                           + ((bflo(A1) + bfhi(A1)) + (bflo(B1) + bfhi(B1)));
                    pswap(A0, B0);   // A0 -> frag word0, B0 -> frag word2
                    pswap(A1, B1);   // A1 -> frag word1, B1 -> frag word3
                    bf16x8 pa;
                    uint4 u = { A0, A1, B0, B1 };
                    __builtin_memcpy(&pa, &u, 16);
                    const int kc = kh * 2 + kq;
                    const int cv = ((((kc * 2) | h) ^ l7) << 3);    // swizzled V chunk
#pragma unroll
                    for (int dt = 0; dt < 4; ++dt) {   // 4 independent o_acc chains
                        const bf16x8 vf = *(const bf16x8*)(vb + (dt * 32 + q5) * 64 + cv);
                        o_acc[dt] = __builtin_amdgcn_mfma_f32_32x32x16_bf16(pa, vf, o_acc[dt], 0, 0, 0);
                    }
                }
            };

            HALF(0, diag && (rt2 == 0));
            if (!diagw) HALF(1, diag && (rt2 == 1));

            __syncthreads();   // vmcnt(0) drain waits the DMA issued ABOVE (full compute behind it)
            j = jn; ++it;
        }

        // ---- epilogue: full l per q-row, then lane-local normalize
        // llane(q5,h) holds the h-subset of Sum_k P-hat[q5][k]; partner has complement.
        unsigned lu; __builtin_memcpy(&lu, &llane, 4);
        unsigned la = lu, lb = lu;
        pswap(la, lb);
        float fa, fb; __builtin_memcpy(&fa, &la, 4); __builtin_memcpy(&fb, &lb, 4);
        const float l_q5 = fa + fb;            // every lane: full l for q-row q5
        int lfull_i; __builtin_memcpy(&lfull_i, &l_q5, 4);

        const int rowbase = qb * BLK_ + rt2 * 32;
#pragma unroll
        for (int r = 0; r < 16; ++r) {
            const int cb  = (r & 3) + 8 * (r >> 2);           // compile-time
            const int crow = cb + 4 * h;                      // q-row of this acc slot
            const int li = __builtin_amdgcn_ds_bpermute(crow << 2, lfull_i);
            float lr; __builtin_memcpy(&lr, &li, 4);
            const float inv = 1.0f / lr;
            const int row = rowbase + crow;
            float* op = outg + ((size_t)(b * SEQ_ + row) * H_ + head) * D_ + q5;
            op[0]  = o_acc[0][r] * inv;
            op[32] = o_acc[1][r] * inv;
            op[64] = o_acc[2][r] * inv;
            op[96] = o_acc[3][r] * inv;
        }
    }
}

// ============ fallback (no workspace): round-4 kernel, unchanged ============
#define KSTR 136
#define VSTR 72
__global__ __launch_bounds__(1024)
void sparse_attn_v1(const float* __restrict__ qg, const float* __restrict__ kg,
                    const float* __restrict__ vg, float* __restrict__ outg,
                    unsigned* __restrict__ ctr) {
    __shared__ __align__(16) unsigned short Klds[BLK_ * KSTR];
    __shared__ __align__(16) unsigned short Vlds[D_ * VSTR];
    __shared__ __align__(16) unsigned short Plds[16 * 16 * PSTR];
    __shared__ unsigned taskLds;

    const int tid  = threadIdx.x;
    const int wave = tid >> 6;
    const int lane = tid & 63;
    const int l15  = lane & 15;
    const int quad = lane >> 4;
    const int hsub = wave >> 2;
    const int rt   = wave & 3;

    const int srow0 = tid >> 5, srow1 = srow0 + 32;
    const int sc4   = tid & 31;
    const int kld0  = srow0 * KSTR + sc4 * 4, kld1 = srow1 * KSTR + sc4 * 4;
    const int vd    = sc4 * 4;
    const int vskew = (sc4 & 7) << 3;
    const int vp0   = (srow0 + vskew) & 63, vp1 = (srow1 + vskew) & 63;
    const size_t stoff0 = (size_t)srow0 * (HKV_ * D_) + sc4 * 4;
    const size_t stoff1 = (size_t)srow1 * (HKV_ * D_) + sc4 * 4;

    const float c2 = 0.12751649736230723f;
    const short oneb = (short)0x3F80;
    const bf16x8 ones = {oneb, oneb, oneb, oneb, oneb, oneb, oneb, oneb};
    unsigned short* pl = &Plds[wave * 16 * PSTR];

    for (;;) {
        __syncthreads();
        if (tid == 0) taskLds = atomicAdd(ctr, 1u);
        __syncthreads();
        const unsigned t = taskLds;
        if (t >= NTASK) break;
        const int qb  = 31 - (int)(t >> 4);
        const int bh  = (int)(t & 15);
        const int b   = bh >> 3;
        const int hkv = bh & 7;
        const int head = hkv * 4 + hsub;
        const float* kbase = kg + ((size_t)(b * SEQ_) * HKV_ + hkv) * D_;
        const float* vbase = vg + ((size_t)(b * SEQ_) * HKV_ + hkv) * D_;
        bf16x8 qf[4];
        {
            const int row = qb * BLK_ + rt * 16 + l15;
            const float* qp = qg + ((size_t)(b * SEQ_ + row) * H_ + head) * D_;
#pragma unroll
            for (int s = 0; s < 4; ++s) {
                const float4 a = *(const float4*)(qp + s * 32 + quad * 8);
                const float4 c = *(const float4*)(qp + s * 32 + quad * 8 + 4);
                uint4 u = { pk2(a.x, a.y), pk2(a.z, a.w), pk2(c.x, c.y), pk2(c.z, c.w) };
                __builtin_memcpy(&qf[s], &u, 16);
            }
        }
        f32x4 lacc = f32x4{0.f, 0.f, 0.f, 0.f};
        f32x4 o_acc[8];
#pragma unroll
        for (int t8 = 0; t8 < 8; ++t8) o_acc[t8] = f32x4{0.f, 0.f, 0.f, 0.f};
        int j = next_valid(qb, -1);
        float4 kpr0, kpr1, vpr0, vpr1;
        {
            const float* kp = kbase + (size_t)j * BLK_ * HKV_ * D_;
            const float* vp = vbase + (size_t)j * BLK_ * HKV_ * D_;
            kpr0 = *(const float4*)(kp + stoff0); kpr1 = *(const float4*)(kp + stoff1);
            vpr0 = *(const float4*)(vp + stoff0); vpr1 = *(const float4*)(vp + stoff1);
        }
        while (j <= qb) {
            const int jn = next_valid(qb, j);
            __syncthreads();
            {
                uint2 u0 = { pk2(kpr0.x, kpr0.y), pk2(kpr0.z, kpr0.w) };
                uint2 u1 = { pk2(kpr1.x, kpr1.y), pk2(kpr1.z, kpr1.w) };
                *(uint2*)&Klds[kld0] = u0;
                *(uint2*)&Klds[kld1] = u1;
                unsigned a0 = pk2(vpr0.x, vpr0.y), a1 = pk2(vpr0.z, vpr0.w);
                Vlds[(vd + 0) * VSTR + vp0] = (unsigned short)a0;
                Vlds[(vd + 1) * VSTR + vp0] = (unsigned short)(a0 >> 16);
                Vlds[(vd + 2) * VSTR + vp0] = (unsigned short)a1;
                Vlds[(vd + 3) * VSTR + vp0] = (unsigned short)(a1 >> 16);
                unsigned b0 = pk2(vpr1.x, vpr1.y), b1 = pk2(vpr1.z, vpr1.w);
                Vlds[(vd + 0) * VSTR + vp1] = (unsigned short)b0;
                Vlds[(vd + 1) * VSTR + vp1] = (unsigned short)(b0 >> 16);
                Vlds[(vd + 2) * VSTR + vp1] = (unsigned short)b1;
                Vlds[(vd + 3) * VSTR + vp1] = (unsigned short)(b1 >> 16);
            }
            __syncthreads();
            if (jn <= qb) {
                const float* kp = kbase + (size_t)jn * BLK_ * HKV_ * D_;
                const float* vp = vbase + (size_t)jn * BLK_ * HKV_ * D_;
                kpr0 = *(const float4*)(kp + stoff0); kpr1 = *(const float4*)(kp + stoff1);
                vpr0 = *(const float4*)(vp + stoff0); vpr1 = *(const float4*)(vp + stoff1);
            }
            f32x4 sacc[4];
#pragma unroll
            for (int t4 = 0; t4 < 4; ++t4) {
                f32x4 acc = f32x4{0.f, 0.f, 0.f, 0.f};
#pragma unroll
                for (int s = 0; s < 4; ++s) {
                    const bf16x8 kf = *(const bf16x8*)&Klds[(t4 * 16 + l15) * KSTR + s * 32 + quad * 8];
                    acc = __builtin_amdgcn_mfma_f32_16x16x32_bf16(qf[s], kf, acc, 0, 0, 0);
                }
                sacc[t4] = acc;
            }
            if (j == qb) {
                const int rowbase = rt * 16 + quad * 4;
#pragma unroll
                for (int t4 = 0; t4 < 4; ++t4) {
                    const int col = t4 * 16 + l15;
#pragma unroll
                    for (int r = 0; r < 4; ++r)
                        if (col > rowbase + r) sacc[t4][r] = -INFINITY;
                }
            }
#pragma unroll
            for (int t4 = 0; t4 < 4; ++t4) {
                const float p0 = exp2f(sacc[t4][0] * c2);
                const float p1 = exp2f(sacc[t4][1] * c2);
                const float p2 = exp2f(sacc[t4][2] * c2);
                const float p3 = exp2f(sacc[t4][3] * c2);
                const unsigned u01 = pk2(p0, p1), u23 = pk2(p2, p3);
                const int cb = t4 * 16 + l15;
                pl[(quad * 4 + 0) * PSTR + cb] = (unsigned short)u01;
                pl[(quad * 4 + 1) * PSTR + cb] = (unsigned short)(u01 >> 16);
                pl[(quad * 4 + 2) * PSTR + cb] = (unsigned short)u23;
                pl[(quad * 4 + 3) * PSTR + cb] = (unsigned short)(u23 >> 16);
            }
#pragma unroll
            for (int s2 = 0; s2 < 2; ++s2) {
                const bf16x8 pf = *(const bf16x8*)&pl[l15 * PSTR + s2 * 32 + quad * 8];
                lacc = __builtin_amdgcn_mfma_f32_16x16x32_bf16(pf, ones, lacc, 0, 0, 0);
                const int k0 = s2 * 32 + quad * 8;
#pragma unroll
                for (int t8 = 0; t8 < 8; ++t8) {
                    const int n  = t8 * 16 + l15;
                    const int p2 = (k0 + (((n >> 2) & 7) << 3)) & 63;
                    const bf16x8 vf = *(const bf16x8*)&Vlds[n * VSTR + p2];
                    o_acc[t8] = __builtin_amdgcn_mfma_f32_16x16x32_bf16(pf, vf, o_acc[t8], 0, 0, 0);
                }
            }
            j = jn;
        }
        const int orow = qb * BLK_ + rt * 16 + quad * 4;
#pragma unroll
        for (int r = 0; r < 4; ++r) {
            const float inv_l = 1.0f / lacc[r];
            float* op = outg + ((size_t)(b * SEQ_ + orow + r) * H_ + head) * D_;
#pragma unroll
            for (int t8 = 0; t8 < 8; ++t8)
                op[t8 * 16 + l15] = o_acc[t8][r] * inv_l;
        }
    }
}

extern "C" void kernel_launch(void* const* d_in, const int* in_sizes, int n_in,
                              void* d_out, int out_size, void* d_ws, size_t ws_size,
                              hipStream_t stream) {
    const float* q = (const float*)d_in[0];
    const float* k = (const float*)d_in[1];
    const float* v = (const float*)d_in[2];
    float* out = (float*)d_out;

    const size_t kws_elems = (size_t)B_ * HKV_ * SEQ_ * D_;   // 4,194,304 bf16
    const size_t need = 256 + 2 * kws_elems * sizeof(unsigned short);
    if (ws_size >= need) {
        unsigned short* Kws = (unsigned short*)((char*)d_ws + 256);
        unsigned short* Vws = Kws + kws_elems;
        hipMemsetAsync(d_ws, 0, 256, stream);
        prepass_kernel<<<dim3(B_ * HKV_ * NB_), dim3(256), 0, stream>>>(k, v, Kws, Vws);
        sparse_attn_v8<<<dim3(NBLOCK), dim3(512), 0, stream>>>(q, out, Kws, Vws, (unsigned*)d_ws);
    } else {
        hipMemsetAsync(d_ws, 0, sizeof(unsigned), stream);
        sparse_attn_v1<<<dim3(256), dim3(1024), 0, stream>>>(q, k, v, out, (unsigned*)d_ws);
    }
}

// Round 7
// 296.491 us; speedup vs baseline: 2.4074x; 1.0133x over previous
//
#include <hip/hip_runtime.h>

#define B_    2
#define SEQ_  2048
#define H_    32
#define HKV_  8
#define D_    128
#define BLK_  64
#define NB_   32
#define LOCAL_ 16
#define VERT_  8

#define PSTR 72    // v1 fallback only
#define NTASKW 4096   // wave-tasks: 32 qb x 16 bh x 4 hsub x 2 rt2
#define NBLOCK 256

typedef __attribute__((ext_vector_type(8))) short bf16x8;
typedef __attribute__((ext_vector_type(4))) float f32x4;
typedef __attribute__((ext_vector_type(16))) float f32x16;

__device__ __forceinline__ unsigned short f2bf(float f) {
    union { float f; unsigned u; } x; x.f = f;
    unsigned u = x.u;
    return (unsigned short)((u + 0x7FFFu + ((u >> 16) & 1u)) >> 16);
}

__device__ __forceinline__ unsigned pk2(float a, float b) {
#if defined(__has_builtin) && __has_builtin(__builtin_amdgcn_cvt_pk_bf16_f32)
    typedef __attribute__((ext_vector_type(2))) __bf16 bf2;
    bf2 r = __builtin_amdgcn_cvt_pk_bf16_f32(a, b);
    unsigned u; __builtin_memcpy(&u, &r, 4); return u;
#else
    return (unsigned)f2bf(a) | ((unsigned)f2bf(b) << 16);
#endif
}

// v_permlane32_swap_b32 a, b : new a[32:63] = old b[0:31]; new b[0:31] = old a[32:63].
__device__ __forceinline__ void pswap(unsigned &a, unsigned &b) {
#if defined(__has_builtin) && __has_builtin(__builtin_amdgcn_permlane32_swap)
    auto r = __builtin_amdgcn_permlane32_swap((int)a, (int)b, false, false);
    a = (unsigned)r[0]; b = (unsigned)r[1];
#else
    asm("v_permlane32_swap_b32 %0, %1" : "+v"(a), "+v"(b));
#endif
}

// bf16 halves of a pk2 word back to f32 (exact)
__device__ __forceinline__ float bflo(unsigned u) {
    unsigned v = u << 16; float f; __builtin_memcpy(&f, &v, 4); return f;
}
__device__ __forceinline__ float bfhi(unsigned u) {
    unsigned v = u & 0xFFFF0000u; float f; __builtin_memcpy(&f, &v, 4); return f;
}

__device__ __forceinline__ f32x16 zero16() {
    f32x16 z;
#pragma unroll
    for (int i = 0; i < 16; ++i) z[i] = 0.f;
    return z;
}

__device__ __forceinline__ int next_valid(int qb, int j) {
    for (++j; j <= qb; ++j)
        if (((qb - j) < LOCAL_) || (((j + 1) & (VERT_ - 1)) == 0)) return j;
    return qb + 1;
}

// ============ prepass: K/V -> bf16 in FRAGMENT-NATIVE chunk layouts ============
// K2 per (b,hkv): [j(32)][kh(2)][dk(8)][h(2)][q5(32)][e(8)] ushorts.
//   chunk c = kh*512 + dk*64 + h*32 + q5; element e = K[kv=kh*32+q5][d=dk*16+h*8+e].
//   Main-kernel kf load: K2bh + j*8192 + kh*4096 + dk*512 + lane*8  (lane = h*32+q5)
//   -> one 1KB fully-coalesced global_load_dwordx4 per wave per (kh,dk).
// V2 per (b,hkv): [j(32)][dt(4)][kc(4)][h(2)][q5(32)][e(8)] ushorts.
//   chunk cv = dt*256 + kc*64 + h*32 + q5; element e = V[kv=kc*16+h*8+e][d=dt*32+q5].
//   vf load: V2bh + j*8192 + dt*2048 + kc*512 + lane*8.
__global__ __launch_bounds__(256)
void prepass_kernel(const float* __restrict__ kg, const float* __restrict__ vg,
                    unsigned short* __restrict__ Kws, unsigned short* __restrict__ Vws) {
    __shared__ unsigned short Vt[D_ * 72];   // [d][pos], padded
    const int bid = blockIdx.x;
    const int b   = bid >> 8;
    const int hkv = (bid >> 5) & 7;
    const int jb  = bid & 31;
    const int tid = threadIdx.x;
    const int rs  = HKV_ * D_;   // fp32 row stride

    const float* kbase = kg + ((size_t)(b * SEQ_ + jb * BLK_) * HKV_ + hkv) * D_;
    const float* vbase = vg + ((size_t)(b * SEQ_ + jb * BLK_) * HKV_ + hkv) * D_;
    unsigned short* Kdst = Kws + ((size_t)(b * 8 + hkv) * NB_ + jb) * (BLK_ * D_);
    unsigned short* Vdst = Vws + ((size_t)(b * 8 + hkv) * NB_ + jb) * (D_ * BLK_);

#pragma unroll
    for (int t = 0; t < 4; ++t) {           // K: 1024 chunks of 8 elems
        const int c  = t * 256 + tid;
        const int q5 = c & 31, h = (c >> 5) & 1, dk = (c >> 6) & 7, kh = (c >> 9) & 1;
        const int kv = kh * 32 + q5;
        const float* p = kbase + (size_t)kv * rs + dk * 16 + h * 8;
        const float4 a = *(const float4*)p;
        const float4 d4 = *(const float4*)(p + 4);
        uint4 u = { pk2(a.x, a.y), pk2(a.z, a.w), pk2(d4.x, d4.y), pk2(d4.z, d4.w) };
        *(uint4*)&Kdst[c * 8] = u;
    }
#pragma unroll
    for (int t = 0; t < 8; ++t) {           // V: load + transpose into LDS ([d][pos])
        const int q = t * 256 + tid;
        const int pos = q >> 5, c4 = q & 31;
        const float4 v4 = *(const float4*)(vbase + (size_t)pos * rs + c4 * 4);
        const unsigned u0 = pk2(v4.x, v4.y), u1 = pk2(v4.z, v4.w);
        Vt[(c4 * 4 + 0) * 72 + pos] = (unsigned short)u0;
        Vt[(c4 * 4 + 1) * 72 + pos] = (unsigned short)(u0 >> 16);
        Vt[(c4 * 4 + 2) * 72 + pos] = (unsigned short)u1;
        Vt[(c4 * 4 + 3) * 72 + pos] = (unsigned short)(u1 >> 16);
    }
    __syncthreads();
#pragma unroll
    for (int t = 0; t < 4; ++t) {           // V out: 1024 chunks of 8 kv-positions
        const int cv = t * 256 + tid;
        const int q5 = cv & 31, h = (cv >> 5) & 1, kc = (cv >> 6) & 3, dt = (cv >> 8) & 3;
        const int d = dt * 32 + q5, pos0 = kc * 16 + h * 8;
        const uint2 q0 = *(const uint2*)&Vt[d * 72 + pos0];
        const uint2 q1 = *(const uint2*)&Vt[d * 72 + pos0 + 4];
        uint4 u = { q0.x, q0.y, q1.x, q1.y };
        *(uint4*)&Vdst[cv * 8] = u;
    }
}

// ============ main kernel v9: no LDS, no barriers, wave-per-task, direct L2 reads ============
// The global_load_lds+drain path capped delivery at ~1.5 TB/s (v2-v6 all ~window ==
// 32KB/rate, invariant to content). v9 removes that path: each MFMA fragment is one
// coalesced 1KB global load from the fragment-native workspace (L2/L3-resident, 32MB
// total). No __shared__, no __syncthreads, no vmcnt drains -> 8 free-running waves/CU.
// Compute/math = v8 (HALF-sequential S, pack-inline pa, VALU-l, bpermute epilogue),
// at v3's register budget (launch_bounds(512,2), no spill).
__global__ __launch_bounds__(512, 2)
void sparse_attn_v9(const float* __restrict__ qg, float* __restrict__ outg,
                    const unsigned short* __restrict__ Kws,
                    const unsigned short* __restrict__ Vws,
                    unsigned* __restrict__ ctr) {
    const int tid  = threadIdx.x;
    const int lane = tid & 63;
    const int q5   = lane & 31;       // q-row in 32-tile / d-col in 32 / kv-row in 32
    const int h    = lane >> 5;

    const float c2 = 0.12751649736230723f;   // (1/sqrt(128)) * log2(e)

    for (;;) {
        unsigned tt = 0;
        if (lane == 0) tt = atomicAdd(ctr, 1u);
        tt = (unsigned)__builtin_amdgcn_readfirstlane((int)tt);
        if (tt >= NTASKW) break;

        const int qb   = 31 - (int)(tt >> 7);   // LPT: big tasks first
        const int rem  = (int)(tt & 127);
        const int bh   = rem >> 3;
        const int wu   = rem & 7;
        const int hsub = wu >> 1;
        const int rt2  = wu & 1;
        const int b    = bh >> 3;
        const int hkv  = bh & 7;
        const int head = hkv * 4 + hsub;

        const unsigned short* Kbh = Kws + (size_t)(b * 8 + hkv) * (NB_ * BLK_ * D_);
        const unsigned short* Vbh = Vws + (size_t)(b * 8 + hkv) * (NB_ * D_ * BLK_);

        // ---- Q fragments (B-operand layout): q-col = q5, d = dk*16 + h*8 + e
        bf16x8 qf[8];
        {
            const int row = qb * BLK_ + rt2 * 32 + q5;
            const float* qp = qg + ((size_t)(b * SEQ_ + row) * H_ + head) * D_ + h * 8;
#pragma unroll
            for (int dk = 0; dk < 8; ++dk) {
                const float4 a = *(const float4*)(qp + dk * 16);
                const float4 c = *(const float4*)(qp + dk * 16 + 4);
                uint4 u = { pk2(a.x, a.y), pk2(a.z, a.w), pk2(c.x, c.y), pk2(c.z, c.w) };
                __builtin_memcpy(&qf[dk], &u, 16);
            }
        }

        float llane = 0.f;
        f32x16 o_acc[4];
#pragma unroll
        for (int dt = 0; dt < 4; ++dt) o_acc[dt] = zero16();

        int j = next_valid(qb, -1);
        while (j <= qb) {
            const int jn = next_valid(qb, j);
            const bool diag  = (j == qb);
            const bool diagw = diag && (rt2 == 0);   // upper 32 k-cols fully masked -> skip kh=1

            const unsigned short* kj = Kbh + (size_t)j * 8192 + lane * 8;
            const unsigned short* vj = Vbh + (size_t)j * 8192 + lane * 8;

            // ---- one 32-col k-half: S^T -> exp -> pack -> PV
            auto HALF = [&](int kh, bool maskit) {
                f32x16 s = zero16();
#pragma unroll
                for (int dk = 0; dk < 8; ++dk) {
                    const bf16x8 kf = *(const bf16x8*)(kj + kh * 4096 + dk * 512);
                    s = __builtin_amdgcn_mfma_f32_32x32x16_bf16(kf, qf[dk], s, 0, 0, 0);
                }
                if (maskit) {
#pragma unroll
                    for (int r = 0; r < 16; ++r) {
                        const int crow = (r & 3) + 8 * (r >> 2) + 4 * h;
                        if (crow > q5) s[r] = -INFINITY;
                    }
                }
#pragma unroll
                for (int r = 0; r < 16; ++r) s[r] = exp2f(s[r] * c2);

#pragma unroll
                for (int kq = 0; kq < 2; ++kq) {
                    const int b0 = kq * 8;
                    unsigned A0 = pk2(s[b0 + 0], s[b0 + 1]);
                    unsigned B0 = pk2(s[b0 + 4], s[b0 + 5]);
                    unsigned A1 = pk2(s[b0 + 2], s[b0 + 3]);
                    unsigned B1 = pk2(s[b0 + 6], s[b0 + 7]);
                    // l accumulate from PRE-swap rounded words (lane-local P-hat values)
                    llane += ((bflo(A0) + bfhi(A0)) + (bflo(B0) + bfhi(B0)))
                           + ((bflo(A1) + bfhi(A1)) + (bflo(B1) + bfhi(B1)));
                    pswap(A0, B0);   // A0 -> frag word0, B0 -> frag word2
                    pswap(A1, B1);   // A1 -> frag word1, B1 -> frag word3
                    bf16x8 pa;
                    uint4 u = { A0, A1, B0, B1 };
                    __builtin_memcpy(&pa, &u, 16);
                    const int kc = kh * 2 + kq;
#pragma unroll
                    for (int dt = 0; dt < 4; ++dt) {   // 4 independent o_acc chains
                        const bf16x8 vf = *(const bf16x8*)(vj + dt * 2048 + kc * 512);
                        o_acc[dt] = __builtin_amdgcn_mfma_f32_32x32x16_bf16(pa, vf, o_acc[dt], 0, 0, 0);
                    }
                }
            };

            HALF(0, diag && (rt2 == 0));
            if (!diagw) HALF(1, diag && (rt2 == 1));

            j = jn;
        }

        // ---- epilogue: full l per q-row (pswap partner exchange), lane-local normalize
        unsigned lu; __builtin_memcpy(&lu, &llane, 4);
        unsigned la = lu, lb = lu;
        pswap(la, lb);
        float fa, fb; __builtin_memcpy(&fa, &la, 4); __builtin_memcpy(&fb, &lb, 4);
        const float l_q5 = fa + fb;            // every lane: full l for q-row q5
        int lfull_i; __builtin_memcpy(&lfull_i, &l_q5, 4);

        const int rowbase = qb * BLK_ + rt2 * 32;
#pragma unroll
        for (int r = 0; r < 16; ++r) {
            const int cb   = (r & 3) + 8 * (r >> 2);          // compile-time
            const int crow = cb + 4 * h;                      // q-row of this acc slot
            const int li = __builtin_amdgcn_ds_bpermute(crow << 2, lfull_i);
            float lr; __builtin_memcpy(&lr, &li, 4);
            const float inv = 1.0f / lr;
            const int row = rowbase + crow;
            float* op = outg + ((size_t)(b * SEQ_ + row) * H_ + head) * D_ + q5;
            op[0]  = o_acc[0][r] * inv;
            op[32] = o_acc[1][r] * inv;
            op[64] = o_acc[2][r] * inv;
            op[96] = o_acc[3][r] * inv;
        }
    }
}

// ============ fallback (no workspace): round-4 kernel, unchanged ============
#define KSTR 136
#define VSTR 72
#define NTASK 512
__global__ __launch_bounds__(1024)
void sparse_attn_v1(const float* __restrict__ qg, const float* __restrict__ kg,
                    const float* __restrict__ vg, float* __restrict__ outg,
                    unsigned* __restrict__ ctr) {
    __shared__ __align__(16) unsigned short Klds[BLK_ * KSTR];
    __shared__ __align__(16) unsigned short Vlds[D_ * VSTR];
    __shared__ __align__(16) unsigned short Plds[16 * 16 * PSTR];
    __shared__ unsigned taskLds;

    const int tid  = threadIdx.x;
    const int wave = tid >> 6;
    const int lane = tid & 63;
    const int l15  = lane & 15;
    const int quad = lane >> 4;
    const int hsub = wave >> 2;
    const int rt   = wave & 3;

    const int srow0 = tid >> 5, srow1 = srow0 + 32;
    const int sc4   = tid & 31;
    const int kld0  = srow0 * KSTR + sc4 * 4, kld1 = srow1 * KSTR + sc4 * 4;
    const int vd    = sc4 * 4;
    const int vskew = (sc4 & 7) << 3;
    const int vp0   = (srow0 + vskew) & 63, vp1 = (srow1 + vskew) & 63;
    const size_t stoff0 = (size_t)srow0 * (HKV_ * D_) + sc4 * 4;
    const size_t stoff1 = (size_t)srow1 * (HKV_ * D_) + sc4 * 4;

    const float c2 = 0.12751649736230723f;
    const short oneb = (short)0x3F80;
    const bf16x8 ones = {oneb, oneb, oneb, oneb, oneb, oneb, oneb, oneb};
    unsigned short* pl = &Plds[wave * 16 * PSTR];

    for (;;) {
        __syncthreads();
        if (tid == 0) taskLds = atomicAdd(ctr, 1u);
        __syncthreads();
        const unsigned t = taskLds;
        if (t >= NTASK) break;
        const int qb  = 31 - (int)(t >> 4);
        const int bh  = (int)(t & 15);
        const int b   = bh >> 3;
        const int hkv = bh & 7;
        const int head = hkv * 4 + hsub;
        const float* kbase = kg + ((size_t)(b * SEQ_) * HKV_ + hkv) * D_;
        const float* vbase = vg + ((size_t)(b * SEQ_) * HKV_ + hkv) * D_;
        bf16x8 qf[4];
        {
            const int row = qb * BLK_ + rt * 16 + l15;
            const float* qp = qg + ((size_t)(b * SEQ_ + row) * H_ + head) * D_;
#pragma unroll
            for (int s = 0; s < 4; ++s) {
                const float4 a = *(const float4*)(qp + s * 32 + quad * 8);
                const float4 c = *(const float4*)(qp + s * 32 + quad * 8 + 4);
                uint4 u = { pk2(a.x, a.y), pk2(a.z, a.w), pk2(c.x, c.y), pk2(c.z, c.w) };
                __builtin_memcpy(&qf[s], &u, 16);
            }
        }
        f32x4 lacc = f32x4{0.f, 0.f, 0.f, 0.f};
        f32x4 o_acc[8];
#pragma unroll
        for (int t8 = 0; t8 < 8; ++t8) o_acc[t8] = f32x4{0.f, 0.f, 0.f, 0.f};
        int j = next_valid(qb, -1);
        float4 kpr0, kpr1, vpr0, vpr1;
        {
            const float* kp = kbase + (size_t)j * BLK_ * HKV_ * D_;
            const float* vp = vbase + (size_t)j * BLK_ * HKV_ * D_;
            kpr0 = *(const float4*)(kp + stoff0); kpr1 = *(const float4*)(kp + stoff1);
            vpr0 = *(const float4*)(vp + stoff0); vpr1 = *(const float4*)(vp + stoff1);
        }
        while (j <= qb) {
            const int jn = next_valid(qb, j);
            __syncthreads();
            {
                uint2 u0 = { pk2(kpr0.x, kpr0.y), pk2(kpr0.z, kpr0.w) };
                uint2 u1 = { pk2(kpr1.x, kpr1.y), pk2(kpr1.z, kpr1.w) };
                *(uint2*)&Klds[kld0] = u0;
                *(uint2*)&Klds[kld1] = u1;
                unsigned a0 = pk2(vpr0.x, vpr0.y), a1 = pk2(vpr0.z, vpr0.w);
                Vlds[(vd + 0) * VSTR + vp0] = (unsigned short)a0;
                Vlds[(vd + 1) * VSTR + vp0] = (unsigned short)(a0 >> 16);
                Vlds[(vd + 2) * VSTR + vp0] = (unsigned short)a1;
                Vlds[(vd + 3) * VSTR + vp0] = (unsigned short)(a1 >> 16);
                unsigned b0 = pk2(vpr1.x, vpr1.y), b1 = pk2(vpr1.z, vpr1.w);
                Vlds[(vd + 0) * VSTR + vp1] = (unsigned short)b0;
                Vlds[(vd + 1) * VSTR + vp1] = (unsigned short)(b0 >> 16);
                Vlds[(vd + 2) * VSTR + vp1] = (unsigned short)b1;
                Vlds[(vd + 3) * VSTR + vp1] = (unsigned short)(b1 >> 16);
            }
            __syncthreads();
            if (jn <= qb) {
                const float* kp = kbase + (size_t)jn * BLK_ * HKV_ * D_;
                const float* vp = vbase + (size_t)jn * BLK_ * HKV_ * D_;
                kpr0 = *(const float4*)(kp + stoff0); kpr1 = *(const float4*)(kp + stoff1);
                vpr0 = *(const float4*)(vp + stoff0); vpr1 = *(const float4*)(vp + stoff1);
            }
            f32x4 sacc[4];
#pragma unroll
            for (int t4 = 0; t4 < 4; ++t4) {
                f32x4 acc = f32x4{0.f, 0.f, 0.f, 0.f};
#pragma unroll
                for (int s = 0; s < 4; ++s) {
                    const bf16x8 kf = *(const bf16x8*)&Klds[(t4 * 16 + l15) * KSTR + s * 32 + quad * 8];
                    acc = __builtin_amdgcn_mfma_f32_16x16x32_bf16(qf[s], kf, acc, 0, 0, 0);
                }
                sacc[t4] = acc;
            }
            if (j == qb) {
                const int rowbase = rt * 16 + quad * 4;
#pragma unroll
                for (int t4 = 0; t4 < 4; ++t4) {
                    const int col = t4 * 16 + l15;
#pragma unroll
                    for (int r = 0; r < 4; ++r)
                        if (col > rowbase + r) sacc[t4][r] = -INFINITY;
                }
            }
#pragma unroll
            for (int t4 = 0; t4 < 4; ++t4) {
                const float p0 = exp2f(sacc[t4][0] * c2);
                const float p1 = exp2f(sacc[t4][1] * c2);
                const float p2 = exp2f(sacc[t4][2] * c2);
                const float p3 = exp2f(sacc[t4][3] * c2);
                const unsigned u01 = pk2(p0, p1), u23 = pk2(p2, p3);
                const int cb = t4 * 16 + l15;
                pl[(quad * 4 + 0) * PSTR + cb] = (unsigned short)u01;
                pl[(quad * 4 + 1) * PSTR + cb] = (unsigned short)(u01 >> 16);
                pl[(quad * 4 + 2) * PSTR + cb] = (unsigned short)u23;
                pl[(quad * 4 + 3) * PSTR + cb] = (unsigned short)(u23 >> 16);
            }
#pragma unroll
            for (int s2 = 0; s2 < 2; ++s2) {
                const bf16x8 pf = *(const bf16x8*)&pl[l15 * PSTR + s2 * 32 + quad * 8];
                lacc = __builtin_amdgcn_mfma_f32_16x16x32_bf16(pf, ones, lacc, 0, 0, 0);
                const int k0 = s2 * 32 + quad * 8;
#pragma unroll
                for (int t8 = 0; t8 < 8; ++t8) {
                    const int n  = t8 * 16 + l15;
                    const int p2 = (k0 + (((n >> 2) & 7) << 3)) & 63;
                    const bf16x8 vf = *(const bf16x8*)&Vlds[n * VSTR + p2];
                    o_acc[t8] = __builtin_amdgcn_mfma_f32_16x16x32_bf16(pf, vf, o_acc[t8], 0, 0, 0);
                }
            }
            j = jn;
        }
        const int orow = qb * BLK_ + rt * 16 + quad * 4;
#pragma unroll
        for (int r = 0; r < 4; ++r) {
            const float inv_l = 1.0f / lacc[r];
            float* op = outg + ((size_t)(b * SEQ_ + orow + r) * H_ + head) * D_;
#pragma unroll
            for (int t8 = 0; t8 < 8; ++t8)
                op[t8 * 16 + l15] = o_acc[t8][r] * inv_l;
        }
    }
}

extern "C" void kernel_launch(void* const* d_in, const int* in_sizes, int n_in,
                              void* d_out, int out_size, void* d_ws, size_t ws_size,
                              hipStream_t stream) {
    const float* q = (const float*)d_in[0];
    const float* k = (const float*)d_in[1];
    const float* v = (const float*)d_in[2];
    float* out = (float*)d_out;

    const size_t kws_elems = (size_t)B_ * HKV_ * SEQ_ * D_;   // 4,194,304 bf16
    const size_t need = 256 + 2 * kws_elems * sizeof(unsigned short);
    if (ws_size >= need) {
        unsigned short* Kws = (unsigned short*)((char*)d_ws + 256);
        unsigned short* Vws = Kws + kws_elems;
        hipMemsetAsync(d_ws, 0, 256, stream);
        prepass_kernel<<<dim3(B_ * HKV_ * NB_), dim3(256), 0, stream>>>(k, v, Kws, Vws);
        sparse_attn_v9<<<dim3(NBLOCK), dim3(512), 0, stream>>>(q, out, Kws, Vws, (unsigned*)d_ws);
    } else {
        hipMemsetAsync(d_ws, 0, sizeof(unsigned), stream);
        sparse_attn_v1<<<dim3(256), dim3(1024), 0, stream>>>(q, k, v, out, (unsigned*)d_ws);
    }
}

// Round 8
// 278.187 us; speedup vs baseline: 2.5658x; 1.0658x over previous
//
#include <hip/hip_runtime.h>

#define B_    2
#define SEQ_  2048
#define H_    32
#define HKV_  8
#define D_    128
#define BLK_  64
#define NB_   32
#define LOCAL_ 16
#define VERT_  8

#define PSTR 72    // P LDS row stride (multiple of 8 for 16B-aligned b128 reads)
#define NTASK 512
#define NBLOCK 256

typedef __attribute__((ext_vector_type(8))) short bf16x8;
typedef __attribute__((ext_vector_type(4))) float f32x4;

__device__ __forceinline__ unsigned short f2bf(float f) {
    union { float f; unsigned u; } x; x.f = f;
    unsigned u = x.u;
    return (unsigned short)((u + 0x7FFFu + ((u >> 16) & 1u)) >> 16);
}

__device__ __forceinline__ unsigned pk2(float a, float b) {
#if defined(__has_builtin) && __has_builtin(__builtin_amdgcn_cvt_pk_bf16_f32)
    typedef __attribute__((ext_vector_type(2))) __bf16 bf2;
    bf2 r = __builtin_amdgcn_cvt_pk_bf16_f32(a, b);
    unsigned u; __builtin_memcpy(&u, &r, 4); return u;
#else
    return (unsigned)f2bf(a) | ((unsigned)f2bf(b) << 16);
#endif
}

__device__ __forceinline__ int next_valid(int qb, int j) {
    for (++j; j <= qb; ++j)
        if (((qb - j) < LOCAL_) || (((j + 1) & (VERT_ - 1)) == 0)) return j;
    return qb + 1;
}

// async global->LDS DMA, 16B/lane. ldsptr MUST be wave-uniform (HW places lane i at base+i*16).
__device__ __forceinline__ void dma16(const unsigned short* g, unsigned short* l) {
    __builtin_amdgcn_global_load_lds(
        (const __attribute__((address_space(1))) unsigned int*)g,
        (__attribute__((address_space(3))) unsigned int*)l, 16, 0, 0);
}

// ============ prepass ============
// K_ws: [(b*8+hkv)*2048 + row][128], row's 16 16B-chunks stored at chunk^(row&15)   (as round-0)
// V_ws: FRAGMENT-NATIVE for direct global PV reads (no LDS staging in main kernel):
//   per (b,hkv) per tile j: [t8(8)][s2(2)][lane(64)][e(8)] ushorts (8192/tile).
//   element e of chunk (t8,s2,lane): V[kv = s2*32 + (lane>>4)*8 + e][d = t8*16 + (lane&15)]
//   -> main-kernel vf = one coalesced 1KB global_load_dwordx4 at
//      Vbh + j*8192 + (t8*2+s2)*512 + lane*8   (exactly the 16x16x32 B-fragment).
// Also zeroes the task counter (folds out the memset launch).
__global__ __launch_bounds__(256)
void prepass_kernel(const float* __restrict__ kg, const float* __restrict__ vg,
                    unsigned short* __restrict__ Kws, unsigned short* __restrict__ Vws,
                    unsigned* __restrict__ ctr) {
    __shared__ unsigned short Vt[D_ * 72];   // [d][pos], padded
    const int bid = blockIdx.x;
    const int b   = bid >> 8;
    const int hkv = (bid >> 5) & 7;
    const int jb  = bid & 31;
    const int tid = threadIdx.x;
    const int rs  = HKV_ * D_;   // fp32 row stride

    if (bid == 0 && tid == 0) *ctr = 0;   // main kernel launches after prepass completes

    const float* kbase = kg + ((size_t)(b * SEQ_ + jb * BLK_) * HKV_ + hkv) * D_;
    const float* vbase = vg + ((size_t)(b * SEQ_ + jb * BLK_) * HKV_ + hkv) * D_;
    unsigned short* Kdst = Kws + ((size_t)(b * 8 + hkv) * SEQ_ + jb * BLK_) * D_;
    unsigned short* Vdst = Vws + ((size_t)(b * 8 + hkv) * NB_ + jb) * (D_ * BLK_);

#pragma unroll
    for (int t = 0; t < 4; ++t) {           // K: 1024 chunks of 8 elems (round-0 layout)
        const int q = t * 256 + tid;
        const int row = q >> 4, c = q & 15;
        const float* p = kbase + (size_t)row * rs + c * 8;
        const float4 a = *(const float4*)p;
        const float4 d4 = *(const float4*)(p + 4);
        uint4 u = { pk2(a.x, a.y), pk2(a.z, a.w), pk2(d4.x, d4.y), pk2(d4.z, d4.w) };
        *(uint4*)&Kdst[row * 128 + ((c ^ (row & 15)) << 3)] = u;
    }
#pragma unroll
    for (int t = 0; t < 8; ++t) {           // V: load + transpose into LDS  [d][pos]
        const int q = t * 256 + tid;
        const int pos = q >> 5, c4 = q & 31;
        const float4 v4 = *(const float4*)(vbase + (size_t)pos * rs + c4 * 4);
        const unsigned u0 = pk2(v4.x, v4.y), u1 = pk2(v4.z, v4.w);
        Vt[(c4 * 4 + 0) * 72 + pos] = (unsigned short)u0;
        Vt[(c4 * 4 + 1) * 72 + pos] = (unsigned short)(u0 >> 16);
        Vt[(c4 * 4 + 2) * 72 + pos] = (unsigned short)u1;
        Vt[(c4 * 4 + 3) * 72 + pos] = (unsigned short)(u1 >> 16);
    }
    __syncthreads();
#pragma unroll
    for (int t = 0; t < 4; ++t) {           // V out: fragment-native chunks
        const int cv  = t * 256 + tid;       // 0..1023
        const int l15 = cv & 15, quad = (cv >> 4) & 3, s2 = (cv >> 6) & 1, t8 = (cv >> 7) & 7;
        const int d    = t8 * 16 + l15;
        const int pos0 = s2 * 32 + quad * 8;
        const uint2 q0 = *(const uint2*)&Vt[d * 72 + pos0];
        const uint2 q1 = *(const uint2*)&Vt[d * 72 + pos0 + 4];
        uint4 u = { q0.x, q0.y, q1.x, q1.y };
        *(uint4*)&Vdst[cv * 8] = u;
    }
}

// ============ main kernel v10: round-0 v2 structure, V direct-from-global (no V LDS) ============
// The proven 16-wave 16x16 kernel (119us), single ablation: V staging removed. Per window
// the block's 16 waves read the same 16KB V tile via coalesced global loads -> L1-resident;
// the V stream moves to the TA/L1 pipe, off the LDS pipe's critical path, and the barrier
// drain payload halves (K-only DMA, 16KB/window).
__global__ __launch_bounds__(1024)
void sparse_attn_v10(const float* __restrict__ qg, float* __restrict__ outg,
                     const unsigned short* __restrict__ Kws,
                     const unsigned short* __restrict__ Vws,
                     unsigned* __restrict__ ctr) {
    __shared__ __align__(16) unsigned short Kb[2][BLK_ * D_];     // 2 x 16 KB
    __shared__ __align__(16) unsigned short Plds[16 * 16 * PSTR]; // 36.9 KB
    __shared__ unsigned taskLds;

    const int tid  = threadIdx.x;
    const int wave = tid >> 6;
    const int lane = tid & 63;
    const int l15  = lane & 15;
    const int quad = lane >> 4;
    const int hsub = wave >> 2;
    const int rt   = wave & 3;

    // swizzled K chunk offsets (in ushort elems) for this lane
    int csk[4];
#pragma unroll
    for (int s = 0; s < 4; ++s)  csk[s] = ((4 * s + quad) ^ l15) << 3;

    const float c2 = 0.12751649736230723f;   // (1/sqrt(128)) * log2(e)
    const short oneb = (short)0x3F80;
    const bf16x8 ones = {oneb, oneb, oneb, oneb, oneb, oneb, oneb, oneb};
    unsigned short* pl = &Plds[wave * 16 * PSTR];

    for (;;) {
        __syncthreads();
        if (tid == 0) taskLds = atomicAdd(ctr, 1u);
        __syncthreads();
        const unsigned t = taskLds;
        if (t >= NTASK) break;

        const int qb  = 31 - (int)(t >> 4);   // LPT: big tasks first
        const int bh  = (int)(t & 15);
        const int b   = bh >> 3;
        const int hkv = bh & 7;
        const int head = hkv * 4 + hsub;

        const unsigned short* Kbh = Kws + (size_t)(b * 8 + hkv) * SEQ_ * D_;
        const unsigned short* Vbh = Vws + (size_t)(b * 8 + hkv) * NB_ * (D_ * BLK_);
        const unsigned short* Vln = Vbh + lane * 8;   // lane-fixed part of vf address

        int j = next_valid(qb, -1);
        // issue first K-tile DMA into buf0 (latency hidden behind Q load/convert)
        dma16(Kbh + (size_t)j * (BLK_ * D_) + tid * 8, &Kb[0][wave * 512]);

        // ---- Q fragments (A-layout), 16 rows for this wave
        bf16x8 qf[4];
        {
            const int row = qb * BLK_ + rt * 16 + l15;
            const float* qp = qg + ((size_t)(b * SEQ_ + row) * H_ + head) * D_;
#pragma unroll
            for (int s = 0; s < 4; ++s) {
                const float4 a = *(const float4*)(qp + s * 32 + quad * 8);
                const float4 c = *(const float4*)(qp + s * 32 + quad * 8 + 4);
                uint4 u = { pk2(a.x, a.y), pk2(a.z, a.w), pk2(c.x, c.y), pk2(c.z, c.w) };
                __builtin_memcpy(&qf[s], &u, 16);
            }
        }

        f32x4 lacc = f32x4{0.f, 0.f, 0.f, 0.f};
        f32x4 o_acc[8];
#pragma unroll
        for (int t8 = 0; t8 < 8; ++t8) o_acc[t8] = f32x4{0.f, 0.f, 0.f, 0.f};

        __syncthreads();   // drains first DMA (vmcnt(0)) + syncs all waves
        int it = 0;
        while (j <= qb) {
            const int jn = next_valid(qb, j);
            const int cur = it & 1;
            if (jn <= qb)   // issue next K tile into the other buffer (wave-uniform branch)
                dma16(Kbh + (size_t)jn * (BLK_ * D_) + tid * 8, &Kb[cur ^ 1][wave * 512]);

            // ---- S = Q K^T (swizzled conflict-free b128 reads)
            const unsigned short* kb = Kb[cur];
            f32x4 sacc[4];
#pragma unroll
            for (int t4 = 0; t4 < 4; ++t4) {
                f32x4 acc = f32x4{0.f, 0.f, 0.f, 0.f};
                const unsigned short* krow = kb + (t4 * 16 + l15) * 128;
#pragma unroll
                for (int s = 0; s < 4; ++s) {
                    const bf16x8 kf = *(const bf16x8*)(krow + csk[s]);
                    acc = __builtin_amdgcn_mfma_f32_16x16x32_bf16(qf[s], kf, acc, 0, 0, 0);
                }
                sacc[t4] = acc;
            }

            if (j == qb) {   // diagonal block: token-level causal mask
                const int rowbase = rt * 16 + quad * 4;
#pragma unroll
                for (int t4 = 0; t4 < 4; ++t4) {
                    const int col = t4 * 16 + l15;
#pragma unroll
                    for (int r = 0; r < 4; ++r)
                        if (col > rowbase + r) sacc[t4][r] = -INFINITY;
                }
            }

            // ---- P = exp2(c2*S) unnormalized -> LDS (C-layout -> A-layout)
#pragma unroll
            for (int t4 = 0; t4 < 4; ++t4) {
                const float p0 = exp2f(sacc[t4][0] * c2);
                const float p1 = exp2f(sacc[t4][1] * c2);
                const float p2 = exp2f(sacc[t4][2] * c2);
                const float p3 = exp2f(sacc[t4][3] * c2);
                const unsigned u01 = pk2(p0, p1), u23 = pk2(p2, p3);
                const int cb = t4 * 16 + l15;
                pl[(quad * 4 + 0) * PSTR + cb] = (unsigned short)u01;
                pl[(quad * 4 + 1) * PSTR + cb] = (unsigned short)(u01 >> 16);
                pl[(quad * 4 + 2) * PSTR + cb] = (unsigned short)u23;
                pl[(quad * 4 + 3) * PSTR + cb] = (unsigned short)(u23 >> 16);
            }
            // compiler inserts precise lgkmcnt for the P write->read dependency

            // ---- O += P V ; l += P*ones.  vf = direct global (fragment-native, L1-hit)
            const unsigned short* vj = Vln + (size_t)j * (D_ * BLK_);
#pragma unroll
            for (int s2 = 0; s2 < 2; ++s2) {
                const bf16x8 pf = *(const bf16x8*)&pl[l15 * PSTR + s2 * 32 + quad * 8];
                lacc = __builtin_amdgcn_mfma_f32_16x16x32_bf16(pf, ones, lacc, 0, 0, 0);
#pragma unroll
                for (int t8 = 0; t8 < 8; ++t8) {
                    const bf16x8 vf = *(const bf16x8*)(vj + (t8 * 2 + s2) * 512);
                    o_acc[t8] = __builtin_amdgcn_mfma_f32_16x16x32_bf16(pf, vf, o_acc[t8], 0, 0, 0);
                }
            }

            __syncthreads();   // drains the K DMA issued ABOVE (full compute behind it)
            j = jn; ++it;
        }

        // ---- epilogue
        const int orow = qb * BLK_ + rt * 16 + quad * 4;
#pragma unroll
        for (int r = 0; r < 4; ++r) {
            const float inv_l = 1.0f / lacc[r];
            float* op = outg + ((size_t)(b * SEQ_ + orow + r) * H_ + head) * D_;
#pragma unroll
            for (int t8 = 0; t8 < 8; ++t8)
                op[t8 * 16 + l15] = o_acc[t8][r] * inv_l;
        }
    }
}

// ============ fallback (no workspace): round-4 kernel, unchanged ============
#define KSTR 136
#define VSTR 72
__global__ __launch_bounds__(1024)
void sparse_attn_v1(const float* __restrict__ qg, const float* __restrict__ kg,
                    const float* __restrict__ vg, float* __restrict__ outg,
                    unsigned* __restrict__ ctr) {
    __shared__ __align__(16) unsigned short Klds[BLK_ * KSTR];
    __shared__ __align__(16) unsigned short Vlds[D_ * VSTR];
    __shared__ __align__(16) unsigned short Plds[16 * 16 * PSTR];
    __shared__ unsigned taskLds;

    const int tid  = threadIdx.x;
    const int wave = tid >> 6;
    const int lane = tid & 63;
    const int l15  = lane & 15;
    const int quad = lane >> 4;
    const int hsub = wave >> 2;
    const int rt   = wave & 3;

    const int srow0 = tid >> 5, srow1 = srow0 + 32;
    const int sc4   = tid & 31;
    const int kld0  = srow0 * KSTR + sc4 * 4, kld1 = srow1 * KSTR + sc4 * 4;
    const int vd    = sc4 * 4;
    const int vskew = (sc4 & 7) << 3;
    const int vp0   = (srow0 + vskew) & 63, vp1 = (srow1 + vskew) & 63;
    const size_t stoff0 = (size_t)srow0 * (HKV_ * D_) + sc4 * 4;
    const size_t stoff1 = (size_t)srow1 * (HKV_ * D_) + sc4 * 4;

    const float c2 = 0.12751649736230723f;
    const short oneb = (short)0x3F80;
    const bf16x8 ones = {oneb, oneb, oneb, oneb, oneb, oneb, oneb, oneb};
    unsigned short* pl = &Plds[wave * 16 * PSTR];

    for (;;) {
        __syncthreads();
        if (tid == 0) taskLds = atomicAdd(ctr, 1u);
        __syncthreads();
        const unsigned t = taskLds;
        if (t >= NTASK) break;
        const int qb  = 31 - (int)(t >> 4);
        const int bh  = (int)(t & 15);
        const int b   = bh >> 3;
        const int hkv = bh & 7;
        const int head = hkv * 4 + hsub;
        const float* kbase = kg + ((size_t)(b * SEQ_) * HKV_ + hkv) * D_;
        const float* vbase = vg + ((size_t)(b * SEQ_) * HKV_ + hkv) * D_;
        bf16x8 qf[4];
        {
            const int row = qb * BLK_ + rt * 16 + l15;
            const float* qp = qg + ((size_t)(b * SEQ_ + row) * H_ + head) * D_;
#pragma unroll
            for (int s = 0; s < 4; ++s) {
                const float4 a = *(const float4*)(qp + s * 32 + quad * 8);
                const float4 c = *(const float4*)(qp + s * 32 + quad * 8 + 4);
                uint4 u = { pk2(a.x, a.y), pk2(a.z, a.w), pk2(c.x, c.y), pk2(c.z, c.w) };
                __builtin_memcpy(&qf[s], &u, 16);
            }
        }
        f32x4 lacc = f32x4{0.f, 0.f, 0.f, 0.f};
        f32x4 o_acc[8];
#pragma unroll
        for (int t8 = 0; t8 < 8; ++t8) o_acc[t8] = f32x4{0.f, 0.f, 0.f, 0.f};
        int j = next_valid(qb, -1);
        float4 kpr0, kpr1, vpr0, vpr1;
        {
            const float* kp = kbase + (size_t)j * BLK_ * HKV_ * D_;
            const float* vp = vbase + (size_t)j * BLK_ * HKV_ * D_;
            kpr0 = *(const float4*)(kp + stoff0); kpr1 = *(const float4*)(kp + stoff1);
            vpr0 = *(const float4*)(vp + stoff0); vpr1 = *(const float4*)(vp + stoff1);
        }
        while (j <= qb) {
            const int jn = next_valid(qb, j);
            __syncthreads();
            {
                uint2 u0 = { pk2(kpr0.x, kpr0.y), pk2(kpr0.z, kpr0.w) };
                uint2 u1 = { pk2(kpr1.x, kpr1.y), pk2(kpr1.z, kpr1.w) };
                *(uint2*)&Klds[kld0] = u0;
                *(uint2*)&Klds[kld1] = u1;
                unsigned a0 = pk2(vpr0.x, vpr0.y), a1 = pk2(vpr0.z, vpr0.w);
                Vlds[(vd + 0) * VSTR + vp0] = (unsigned short)a0;
                Vlds[(vd + 1) * VSTR + vp0] = (unsigned short)(a0 >> 16);
                Vlds[(vd + 2) * VSTR + vp0] = (unsigned short)a1;
                Vlds[(vd + 3) * VSTR + vp0] = (unsigned short)(a1 >> 16);
                unsigned b0 = pk2(vpr1.x, vpr1.y), b1 = pk2(vpr1.z, vpr1.w);
                Vlds[(vd + 0) * VSTR + vp1] = (unsigned short)b0;
                Vlds[(vd + 1) * VSTR + vp1] = (unsigned short)(b0 >> 16);
                Vlds[(vd + 2) * VSTR + vp1] = (unsigned short)b1;
                Vlds[(vd + 3) * VSTR + vp1] = (unsigned short)(b1 >> 16);
            }
            __syncthreads();
            if (jn <= qb) {
                const float* kp = kbase + (size_t)jn * BLK_ * HKV_ * D_;
                const float* vp = vbase + (size_t)jn * BLK_ * HKV_ * D_;
                kpr0 = *(const float4*)(kp + stoff0); kpr1 = *(const float4*)(kp + stoff1);
                vpr0 = *(const float4*)(vp + stoff0); vpr1 = *(const float4*)(vp + stoff1);
            }
            f32x4 sacc[4];
#pragma unroll
            for (int t4 = 0; t4 < 4; ++t4) {
                f32x4 acc = f32x4{0.f, 0.f, 0.f, 0.f};
#pragma unroll
                for (int s = 0; s < 4; ++s) {
                    const bf16x8 kf = *(const bf16x8*)&Klds[(t4 * 16 + l15) * KSTR + s * 32 + quad * 8];
                    acc = __builtin_amdgcn_mfma_f32_16x16x32_bf16(qf[s], kf, acc, 0, 0, 0);
                }
                sacc[t4] = acc;
            }
            if (j == qb) {
                const int rowbase = rt * 16 + quad * 4;
#pragma unroll
                for (int t4 = 0; t4 < 4; ++t4) {
                    const int col = t4 * 16 + l15;
#pragma unroll
                    for (int r = 0; r < 4; ++r)
                        if (col > rowbase + r) sacc[t4][r] = -INFINITY;
                }
            }
#pragma unroll
            for (int t4 = 0; t4 < 4; ++t4) {
                const float p0 = exp2f(sacc[t4][0] * c2);
                const float p1 = exp2f(sacc[t4][1] * c2);
                const float p2 = exp2f(sacc[t4][2] * c2);
                const float p3 = exp2f(sacc[t4][3] * c2);
                const unsigned u01 = pk2(p0, p1), u23 = pk2(p2, p3);
                const int cb = t4 * 16 + l15;
                pl[(quad * 4 + 0) * PSTR + cb] = (unsigned short)u01;
                pl[(quad * 4 + 1) * PSTR + cb] = (unsigned short)(u01 >> 16);
                pl[(quad * 4 + 2) * PSTR + cb] = (unsigned short)u23;
                pl[(quad * 4 + 3) * PSTR + cb] = (unsigned short)(u23 >> 16);
            }
#pragma unroll
            for (int s2 = 0; s2 < 2; ++s2) {
                const bf16x8 pf = *(const bf16x8*)&pl[l15 * PSTR + s2 * 32 + quad * 8];
                lacc = __builtin_amdgcn_mfma_f32_16x16x32_bf16(pf, ones, lacc, 0, 0, 0);
                const int k0 = s2 * 32 + quad * 8;
#pragma unroll
                for (int t8 = 0; t8 < 8; ++t8) {
                    const int n  = t8 * 16 + l15;
                    const int p2 = (k0 + (((n >> 2) & 7) << 3)) & 63;
                    const bf16x8 vf = *(const bf16x8*)&Vlds[n * VSTR + p2];
                    o_acc[t8] = __builtin_amdgcn_mfma_f32_16x16x32_bf16(pf, vf, o_acc[t8], 0, 0, 0);
                }
            }
            j = jn;
        }
        const int orow = qb * BLK_ + rt * 16 + quad * 4;
#pragma unroll
        for (int r = 0; r < 4; ++r) {
            const float inv_l = 1.0f / lacc[r];
            float* op = outg + ((size_t)(b * SEQ_ + orow + r) * H_ + head) * D_;
#pragma unroll
            for (int t8 = 0; t8 < 8; ++t8)
                op[t8 * 16 + l15] = o_acc[t8][r] * inv_l;
        }
    }
}

extern "C" void kernel_launch(void* const* d_in, const int* in_sizes, int n_in,
                              void* d_out, int out_size, void* d_ws, size_t ws_size,
                              hipStream_t stream) {
    const float* q = (const float*)d_in[0];
    const float* k = (const float*)d_in[1];
    const float* v = (const float*)d_in[2];
    float* out = (float*)d_out;

    const size_t kws_elems = (size_t)B_ * HKV_ * SEQ_ * D_;   // 4,194,304 bf16
    const size_t need = 256 + 2 * kws_elems * sizeof(unsigned short);
    if (ws_size >= need) {
        unsigned short* Kws = (unsigned short*)((char*)d_ws + 256);
        unsigned short* Vws = Kws + kws_elems;
        prepass_kernel<<<dim3(B_ * HKV_ * NB_), dim3(256), 0, stream>>>(k, v, Kws, Vws, (unsigned*)d_ws);
        sparse_attn_v10<<<dim3(NBLOCK), dim3(1024), 0, stream>>>(q, out, Kws, Vws, (unsigned*)d_ws);
    } else {
        hipMemsetAsync(d_ws, 0, sizeof(unsigned), stream);
        sparse_attn_v1<<<dim3(NBLOCK), dim3(1024), 0, stream>>>(q, k, v, out, (unsigned*)d_ws);
    }
}